// Round 3
// baseline (194.139 us; speedup 1.0000x reference)
//
#include <hip/hip_runtime.h>

// NRC fused encode + 7-layer W=64 MLP. R16 = producer/consumer wave split.
//
// R15 post-mortem: MfmaUtil 40 + VALUBusy 51 = 91% SUMMED -> pipes serialize.
// Cause: all blocks run encode(VALU)->layers(MFMA) in device-wide lockstep, so
// no SIMD ever holds waves in different phases (m114 overlap never triggers).
// MFMA floor 26us + VALU 29us serialized = 55us observed. Overlapped = ~30us.
//
// R16 structure: 8 waves/block = 4 producers (encode) + 4 consumers (MLP).
// Waves round-robin to SIMDs -> every SIMD holds producers AND consumers at
// all times -> VALU and MFMA pipes run concurrently by construction.
//   - SPB=1024, ROUNDS=4 (256 samples/round), grid=1024.
//   - pipeline: consumers compute round r-1 while producers encode round r.
//   - handoff: 16KB staging region (4 consumer slices x 4KB, 2-tile
//     half-exchanges; tile format byte-identical to R15's verified staging).
//   - weights keep their own 48KB -> LDS 64KB/block = 128KB/CU for 2 blocks
//     (no exact-fit risk).
//   - alpha+beta: consumer reloads AL/BE in the epilogue (same f32 math as
//     the old shfl path; memory is at 10% so 24 extra dwords/tile are free).
//   - consumer compute wrapped in s_setprio(1): true role-split regime (T5).
//
// 16x16x32 f16 fragment maps (verified):
//   A[m=lane&15][k=(lane>>4)*8+j], B[k=(lane>>4)*8+j][n=lane&15],
//   D[row=(lane>>4)*4+r][col=lane&15]  (4 blocks mt: row=mt*16+q*4+r)
// Chaining: bf[kt]=concat(relu(pack(acc[2kt])), relu(pack(acc[2kt+1])));
// k-index mismatch absorbed by permuting W1..W5,W6 columns with
// tau(x)=32(x>>5)+16((x&7)>>2)+4((x>>3)&3)+(x&3) at pack time.

typedef _Float16 f16;
typedef f16 f16x2 __attribute__((ext_vector_type(2)));
typedef f16 f16x4 __attribute__((ext_vector_type(4)));
typedef f16 f16x8 __attribute__((ext_vector_type(8)));
typedef float f32x4 __attribute__((ext_vector_type(4)));

#define MFMA32(A, B, C) __builtin_amdgcn_mfma_f32_16x16x32_f16(A, B, C, 0, 0, 0)

static constexpr int TILES  = 4;        // 16-sample tiles per consumer round
static constexpr int WAVES  = 8;        // 4 producers + 4 consumers
static constexpr int BLOCK  = WAVES * 64;    // 512
static constexpr int ROUNDS = 4;
static constexpr int SPB    = ROUNDS * 4 * 64;   // 1024 samples per block

static constexpr int    WUNITS   = 50;      // 48 hidden frag-units + 2 W6
static constexpr int    WCHUNKS  = WUNITS * 64;           // 3200 x 16B
static constexpr size_t WS_BYTES = (size_t)WCHUNKS * 16;  // 51200
static constexpr int    HUNITS   = 48;      // hidden units only -> LDS
static constexpr int    HCHUNKS  = HUNITS * 64;           // 3072
static constexpr int    LDS_WEI  = HUNITS * 1024;         // 49152
static constexpr int    LDS_STG  = 4 * 4096;              // 16384
static constexpr int    LDS_TOT  = LDS_WEI + LDS_STG;     // 65536

__host__ __device__ __forceinline__ int tau(int x) {
    return (x & 32) + ((x & 7) >> 2) * 16 + ((x >> 3) & 3) * 4 + (x & 3);
}

__device__ __forceinline__ f16x2 pkh(float a, float b) {
    return __builtin_bit_cast(f16x2, __builtin_amdgcn_cvt_pkrtz(a, b));
}

__device__ __forceinline__ f16x4 cat22(f16x2 a, f16x2 b) {
    return __builtin_shufflevector(a, b, 0, 1, 2, 3);
}

__device__ __forceinline__ f16x8 cat44(f16x4 a, f16x4 b) {
    return __builtin_shufflevector(a, b, 0, 1, 2, 3, 4, 5, 6, 7);
}

__device__ __forceinline__ f16x4 pack4(f32x4 v) {
    return cat22(pkh(v[0], v[1]), pkh(v[2], v[3]));
}

// atan2(y,x) / (2*pi)
__device__ __forceinline__ float fast_atan2_rev(float y, float x) {
    const float ax = __builtin_fabsf(x), ay = __builtin_fabsf(y);
    const float mx = fmaxf(ax, ay), mn = fminf(ax, ay);
    const float a = mn * __builtin_amdgcn_rcpf(fmaxf(mx, 1e-30f));
    const float s = a * a;
    float r = a * (0.99997726f + s * (-0.33262347f + s * (0.19354346f +
              s * (-0.11643287f + s * (0.05265332f - s * 0.01172120f)))));
    if (ay > ax) r = 1.5707963268f - r;
    if (x < 0.0f) r = 3.1415926536f - r;
    r = (y < 0.0f) ? -r : r;
    return r * 0.15915494309189535f;
}

// acos(x), |err| <= 6.8e-5 rad
__device__ __forceinline__ float fast_acos(float x) {
    const float ax = __builtin_fabsf(x);
    const float t = __builtin_amdgcn_sqrtf(1.0f - ax);
    const float p = t * (1.5707288f + ax * (-0.2121144f +
                    ax * (0.0742610f - ax * 0.0187293f)));
    return (x < 0.0f) ? (3.1415926536f - p) : p;
}

// one-blob: out[i]=exp(-8(x-c_i)^2) via exp ladder (2 transcendentals)
__device__ __forceinline__ void blob4(float x, float* out) {
    const float dx = x - 0.125f;
    const float E0 = __expf(-8.0f * dx * dx);
    const float R  = __expf(4.0f * dx);
    const float t1 = R * 0.60653066f;
    const float t2 = R * 0.22313016f;
    const float t3 = R * 0.082084999f;
    out[0] = E0;
    out[1] = E0 * t1;
    out[2] = out[1] * t2;
    out[3] = out[2] * t3;
}

// compute packed-weight chunk c (= unit*64 + lane2) from the f32 weights
__device__ __forceinline__ f16x8 make_wchunk(
    int c, const float* __restrict__ W0, const float* __restrict__ W1,
    const float* __restrict__ W2, const float* __restrict__ W3,
    const float* __restrict__ W4, const float* __restrict__ W5,
    const float* __restrict__ W6)
{
    const int lane2 = c & 63;
    const int unit  = c >> 6;
    const int q = lane2 >> 4, m = lane2 & 15;
    f16x8 v;
    if (unit < 48) {
        const int l = unit >> 3, kt = (unit & 7) >> 2, mt = unit & 3;
        const float* Ws[6] = {W0, W1, W2, W3, W4, W5};
        const float* __restrict__ Wl = Ws[l];
#pragma unroll
        for (int j = 0; j < 8; ++j) {
            const int x = kt * 32 + q * 8 + j;
            const int src = (l == 0) ? x : tau(x);
            v[j] = (f16)Wl[(mt * 16 + m) * 64 + src];
        }
    } else {
        const int kt = unit - 48;
#pragma unroll
        for (int j = 0; j < 8; ++j) {
            const int src = tau(kt * 32 + q * 8 + j);
            v[j] = (m < 3) ? (f16)W6[m * 64 + src] : (f16)0.0f;
        }
    }
    return v;
}

__global__ __launch_bounds__(256, 1) void pack_weights_kernel(
    const float* __restrict__ W0, const float* __restrict__ W1,
    const float* __restrict__ W2, const float* __restrict__ W3,
    const float* __restrict__ W4, const float* __restrict__ W5,
    const float* __restrict__ W6, f16* __restrict__ ws)
{
    const int c = (int)blockIdx.x * 256 + threadIdx.x;
    if (c >= WCHUNKS) return;
    *(f16x8*)(ws + (size_t)c * 8) = make_wchunk(c, W0, W1, W2, W3, W4, W5, W6);
}

// async global->LDS DMA, 16B per lane. LDS dest is linear per wave:
// HW uses wave-uniform base + lane*16 (guide §5; m97/m104 semantics),
// which matches our chunk layout exactly.
__device__ __forceinline__ void async_ld16(const void* g, void* l) {
    __builtin_amdgcn_global_load_lds(
        (const __attribute__((address_space(1))) void*)g,
        (__attribute__((address_space(3))) void*)l,
        16, 0, 0);
}

template<int PACKED>
__global__ __launch_bounds__(BLOCK, 4) void nrc_mlp_kernel(
    const float* __restrict__ P,  const float* __restrict__ WI,
    const float* __restrict__ NV, const float* __restrict__ AL,
    const float* __restrict__ BE, const float* __restrict__ RR,
    const f16*   __restrict__ ws,
    const float* __restrict__ W0, const float* __restrict__ W1,
    const float* __restrict__ W2, const float* __restrict__ W3,
    const float* __restrict__ W4, const float* __restrict__ W5,
    const float* __restrict__ W6, float* __restrict__ Out)
{
    // [0,48K): packed hidden-weight image. [48K,64K): staging, 4 x 4KB slices.
    __shared__ __attribute__((aligned(16))) unsigned char smem[LDS_TOT];

    const int tid  = threadIdx.x;
    const int lane = tid & 63;
    const int w    = tid >> 6;
    const int q    = lane >> 4;
    const int m    = lane & 15;
    const bool producer = (w < 4);
    const int  cw  = w & 3;          // producer p pairs with consumer p
    const int  blk_base = (int)blockIdx.x * SPB;

    unsigned char* const stg = smem + LDS_WEI;

    // ---- weight image: async DMA (or VALU fallback), issued before encode,
    //      drained by the first round's __syncthreads ----
    if (PACKED) {
#pragma unroll
        for (int i = 0; i < HCHUNKS / BLOCK; ++i) {
            const int c = i * BLOCK + tid;
            async_ld16(ws + (size_t)c * 8, smem + c * 16);
        }
    } else {
#pragma unroll
        for (int i = 0; i < HCHUNKS / BLOCK; ++i) {
            const int c = i * BLOCK + tid;
            *(f16x8*)(smem + c * 16) = make_wchunk(c, W0, W1, W2, W3, W4, W5, W6);
        }
    }

    // ---- W6 fragments: consumer registers only ----
    f16x8 w6f0{}, w6f1{};
    if (!producer) {
        if (PACKED) {
            w6f0 = *(const f16x8*)(ws + (size_t)(HCHUNKS + lane) * 8);
            w6f1 = *(const f16x8*)(ws + (size_t)(HCHUNKS + 64 + lane) * 8);
        } else {
            w6f0 = make_wchunk(HCHUNKS + lane,      W0, W1, W2, W3, W4, W5, W6);
            w6f1 = make_wchunk(HCHUNKS + 64 + lane, W0, W1, W2, W3, W4, W5, W6);
        }
    }

    const f16x4 zero4 = {(f16)0.0f, (f16)0.0f, (f16)0.0f, (f16)0.0f};
    const f32x4 ZF = {0.0f, 0.0f, 0.0f, 0.0f};
    unsigned char* const wb = smem + lane * 16;

    f16x8 bf[TILES][2];   // consumer: one round's B fragments

    // ---- consumer: 6 hidden layers + W6 + scaled store for round rr ----
    auto compute = [&](int rr) {
        __builtin_amdgcn_s_setprio(1);
#pragma unroll
        for (int layer = 0; layer < 6; ++layer) {
            f16x8 wa[8];   // frag index f = kt*4+mt
#pragma unroll
            for (int f = 0; f < 8; ++f)
                wa[f] = *(const f16x8*)(wb + (layer * 8 + f) * 1024);

#pragma unroll
            for (int t = 0; t < TILES; ++t) {
                f32x4 acc[4];
#pragma unroll
                for (int mt = 0; mt < 4; ++mt) {
                    f32x4 z = MFMA32(wa[mt], bf[t][0], ZF);
                    z = MFMA32(wa[4 + mt], bf[t][1], z);
                    acc[mt] = z;
                }
                f16x4 pk[4];
#pragma unroll
                for (int mt = 0; mt < 4; ++mt)
                    pk[mt] = __builtin_elementwise_max(pack4(acc[mt]), zero4);
                bf[t][0] = cat44(pk[0], pk[1]);   // tau absorbed in next layer
                bf[t][1] = cat44(pk[2], pk[3]);
            }
        }
        // epilogue: issue all alpha+beta loads first, then W6 MFMAs + stores
        const int rbase = blk_base + rr * 256 + cw * 64;
        float aa[TILES][3];
#pragma unroll
        for (int t = 0; t < TILES; ++t) {
            const int s = rbase + t * 16 + m;
#pragma unroll
            for (int d = 0; d < 3; ++d)
                aa[t][d] = AL[s * 3 + d] + BE[s * 3 + d];
        }
#pragma unroll
        for (int t = 0; t < TILES; ++t) {
            f32x4 z = MFMA32(w6f0, bf[t][0], ZF);
            z = MFMA32(w6f1, bf[t][1], z);
            if (lane < 16) {   // q==0: D rows r=0..2 = output channels, col m
                const int s = rbase + t * 16 + m;
                float* o = Out + s * 3;
                o[0] = z[0] * aa[t][0];
                o[1] = z[1] * aa[t][1];
                o[2] = z[2] * aa[t][2];
            }
        }
        __builtin_amdgcn_s_setprio(0);
    };

    // ---- pipelined rounds: P encodes r while C computes r-1 ----
    for (int r = 0; r < ROUNDS; ++r) {
        f16x2 hf[32];   // producer: features of sample (lane), packed pairs
        if (producer) {
            const int s = blk_base + r * 256 + cw * 64 + lane;

            float pv[3], wv[3], nv[3], av[3], bv[3];
#pragma unroll
            for (int d = 0; d < 3; ++d) {
                pv[d] = P [s * 3 + d];
                wv[d] = WI[s * 3 + d];
                nv[d] = NV[s * 3 + d];
                av[d] = AL[s * 3 + d];
                bv[d] = BE[s * 3 + d];
            }
            const float rv = RR[s];

            // freq embed: base sin/cos at pi*p (revolutions) + angle doubling
#pragma unroll
            for (int d = 0; d < 3; ++d) {
                float sA[6], cA[6];
                const float fr = __builtin_amdgcn_fractf(pv[d] * 0.5f);
                sA[0] = __builtin_amdgcn_sinf(fr);
                cA[0] = __builtin_amdgcn_cosf(fr);
#pragma unroll
                for (int k = 1; k < 6; ++k) {
                    const float s2 = sA[k-1] * sA[k-1];
                    const float sc = sA[k-1] * cA[k-1];
                    cA[k] = fmaf(-2.0f, s2, 1.0f);
                    sA[k] = sc + sc;
                }
                hf[d * 6 + 0] = pkh(sA[0], sA[1]);
                hf[d * 6 + 1] = pkh(sA[2], sA[3]);
                hf[d * 6 + 2] = pkh(sA[4], sA[5]);
                hf[d * 6 + 3] = pkh(cA[0], cA[1]);
                hf[d * 6 + 4] = pkh(cA[2], cA[3]);
                hf[d * 6 + 5] = pkh(cA[4], cA[5]);
            }
#pragma unroll
            for (int which = 0; which < 2; ++which) {
                const float* dv = (which == 0) ? wv : nv;
                const int ho = 18 + which * 4;
                const float nr = __builtin_amdgcn_sqrtf(dv[0]*dv[0] + dv[1]*dv[1] + dv[2]*dv[2]) + 1e-8f;
                const float u  = fast_atan2_rev(dv[1], dv[0]) + 0.5f;
                float zc = dv[2] * __builtin_amdgcn_rcpf(nr);
                zc = fminf(fmaxf(zc, -1.0f + 1e-6f), 1.0f - 1e-6f);
                const float vv = fast_acos(zc) * 0.3183098861837907f;
                float ob[8];
                blob4(u,  &ob[0]);
                blob4(vv, &ob[4]);
                hf[ho + 0] = pkh(ob[0], ob[1]);
                hf[ho + 1] = pkh(ob[2], ob[3]);
                hf[ho + 2] = pkh(ob[4], ob[5]);
                hf[ho + 3] = pkh(ob[6], ob[7]);
            }
            {
                float ob[4];
                blob4(1.0f - __expf(-rv), ob);
                hf[26] = pkh(ob[0], ob[1]);
                hf[27] = pkh(ob[2], ob[3]);
            }
            hf[28] = pkh(av[0], av[1]);
            hf[29] = pkh(av[2], bv[0]);
            hf[30] = pkh(bv[1], bv[2]);
            hf[31] = pkh(1.0f, 1.0f);
        } else if (r > 0) {
            compute(r - 1);       // overlaps with producers' encode of round r
        }

        // ---- two half-exchanges (2 tiles each) through the staging region.
        // slice layout per consumer: tile t at +t2*2048 (t2 = t&1 within the
        // half), sample m at +m*128, chunk g at dword slot (4g+4m)&31 --
        // byte-identical to the verified R15 staging format.
#pragma unroll
        for (int h = 0; h < 2; ++h) {
            __syncthreads();      // consumers done reading previous contents
            if (producer && ((lane >> 5) == h)) {   // te>>1 == h: 32 lanes
                unsigned char* const tb =
                    stg + cw * 4096 + ((lane >> 4) & 1) * 2048 + m * 128;
#pragma unroll
                for (int g = 0; g < 8; ++g) {
                    const int slot0 = (4 * g + 4 * m) & 31;
                    *(f16x8*)(tb + slot0 * 4) =
                        cat44(cat22(hf[g*4 + 0], hf[g*4 + 1]),
                              cat22(hf[g*4 + 2], hf[g*4 + 3]));
                }
            }
            __syncthreads();      // half-tile staged
            if (!producer) {
#pragma unroll
                for (int t2 = 0; t2 < 2; ++t2) {
#pragma unroll
                    for (int kt = 0; kt < 2; ++kt) {
                        const int s0 = (16 * kt + 4 * q + 4 * m) & 31;
                        bf[h * 2 + t2][kt] = *(const f16x8*)(
                            stg + cw * 4096 + t2 * 2048 + m * 128 + s0 * 4);
                    }
                }
            }
        }
    }
    if (!producer) compute(ROUNDS - 1);   // drain the pipeline
}

extern "C" void kernel_launch(void* const* d_in, const int* in_sizes, int n_in,
                              void* d_out, int out_size, void* d_ws, size_t ws_size,
                              hipStream_t stream) {
    (void)n_in; (void)out_size;
    const float* P  = (const float*)d_in[0];
    const float* WI = (const float*)d_in[1];
    const float* NV = (const float*)d_in[2];
    const float* AL = (const float*)d_in[3];
    const float* BE = (const float*)d_in[4];
    const float* RR = (const float*)d_in[5];
    const float* W0 = (const float*)d_in[6];
    const float* W1 = (const float*)d_in[7];
    const float* W2 = (const float*)d_in[8];
    const float* W3 = (const float*)d_in[9];
    const float* W4 = (const float*)d_in[10];
    const float* W5 = (const float*)d_in[11];
    const float* W6 = (const float*)d_in[12];
    f16*   ws  = (f16*)d_ws;
    float* Out = (float*)d_out;

    const int Bn = in_sizes[0] / 3;     // 1,048,576
    const int grid = Bn / SPB;          // 1024 blocks of 512 threads

    // ws_size fixed per session -> same path every call (graph-safe).
    if (ws_size >= WS_BYTES) {
        hipLaunchKernelGGL(pack_weights_kernel, dim3((WCHUNKS + 255) / 256),
                           dim3(256), 0, stream, W0, W1, W2, W3, W4, W5, W6, ws);
        hipLaunchKernelGGL((nrc_mlp_kernel<1>), dim3(grid), dim3(BLOCK), 0, stream,
                           P, WI, NV, AL, BE, RR, ws,
                           W0, W1, W2, W3, W4, W5, W6, Out);
    } else {
        hipLaunchKernelGGL((nrc_mlp_kernel<0>), dim3(grid), dim3(BLOCK), 0, stream,
                           P, WI, NV, AL, BE, RR, ws,
                           W0, W1, W2, W3, W4, W5, W6, Out);
    }
}

// Round 4
// 179.602 us; speedup vs baseline: 1.0809x; 1.0809x over previous
//
#include <hip/hip_runtime.h>

// NRC fused encode + 7-layer W=64 MLP. R17 = R16 (producer/consumer waves)
// with the register pressure that caused R16's spills surgically removed.
//
// R16 post-mortem: WRITE 12->147MB, FETCH 33->61MB = scratch spills (~16
// dwords/thread/round). Union pressure: hf[32]+bf[32] co-live at barriers,
// consumer peak bf+wa+acc+w6+aa ~ 110+ vs the 128-reg cap of (512,4).
// MfmaUtil 22% x 92us = 20us MFMA-busy -> MFMA stream fine, spills drowned it.
// R17:
//   1. W6 back to LDS (WUNITS=50 staged; LDS 51200+16384=67584, 2 blocks/CU
//      = 135KB <= 160KB). -16 regs in epilogue + kernel-wide live set.
//   2. ROUNDS=8, SPB=2048, grid=512 = exactly 2 blocks/CU, no launch tail,
//      fill/drain amortized 2x, half the per-block weight-image traffic.
//   3. Same staging format / barrier discipline / consumer setprio as R16.
// Peak pressure now ~95 regs (layers: bf32+wa32+acc16+misc) < 128.
//
// Structure: 8 waves/block = 4 producers (encode, VALU) + 4 consumers (MLP,
// MFMA). Waves round-robin to SIMDs -> each SIMD holds 2P+2C from each
// resident block -> VALU and MFMA pipes fed concurrently (m114 overlap).
// Pipeline: consumers compute round r-1 while producers encode round r.
//
// 16x16x32 f16 fragment maps (verified):
//   A[m=lane&15][k=(lane>>4)*8+j], B[k=(lane>>4)*8+j][n=lane&15],
//   D[row=(lane>>4)*4+r][col=lane&15]  (4 blocks mt: row=mt*16+q*4+r)
// Chaining: bf[kt]=concat(relu(pack(acc[2kt])), relu(pack(acc[2kt+1])));
// k-index mismatch absorbed by permuting W1..W5,W6 columns with
// tau(x)=32(x>>5)+16((x&7)>>2)+4((x>>3)&3)+(x&3) at pack time.

typedef _Float16 f16;
typedef f16 f16x2 __attribute__((ext_vector_type(2)));
typedef f16 f16x4 __attribute__((ext_vector_type(4)));
typedef f16 f16x8 __attribute__((ext_vector_type(8)));
typedef float f32x4 __attribute__((ext_vector_type(4)));

#define MFMA32(A, B, C) __builtin_amdgcn_mfma_f32_16x16x32_f16(A, B, C, 0, 0, 0)

static constexpr int TILES  = 4;        // 16-sample tiles per consumer round
static constexpr int WAVES  = 8;        // 4 producers + 4 consumers
static constexpr int BLOCK  = WAVES * 64;    // 512
static constexpr int ROUNDS = 8;
static constexpr int SPB    = ROUNDS * 4 * 64;   // 2048 samples per block

static constexpr int    WUNITS   = 50;      // 48 hidden frag-units + 2 W6
static constexpr int    WCHUNKS  = WUNITS * 64;           // 3200 x 16B
static constexpr size_t WS_BYTES = (size_t)WCHUNKS * 16;  // 51200
static constexpr int    LDS_WEI  = WUNITS * 1024;         // 51200
static constexpr int    LDS_STG  = 4 * 4096;              // 16384
static constexpr int    LDS_TOT  = LDS_WEI + LDS_STG;     // 67584

__host__ __device__ __forceinline__ int tau(int x) {
    return (x & 32) + ((x & 7) >> 2) * 16 + ((x >> 3) & 3) * 4 + (x & 3);
}

__device__ __forceinline__ f16x2 pkh(float a, float b) {
    return __builtin_bit_cast(f16x2, __builtin_amdgcn_cvt_pkrtz(a, b));
}

__device__ __forceinline__ f16x4 cat22(f16x2 a, f16x2 b) {
    return __builtin_shufflevector(a, b, 0, 1, 2, 3);
}

__device__ __forceinline__ f16x8 cat44(f16x4 a, f16x4 b) {
    return __builtin_shufflevector(a, b, 0, 1, 2, 3, 4, 5, 6, 7);
}

__device__ __forceinline__ f16x4 pack4(f32x4 v) {
    return cat22(pkh(v[0], v[1]), pkh(v[2], v[3]));
}

// atan2(y,x) / (2*pi)
__device__ __forceinline__ float fast_atan2_rev(float y, float x) {
    const float ax = __builtin_fabsf(x), ay = __builtin_fabsf(y);
    const float mx = fmaxf(ax, ay), mn = fminf(ax, ay);
    const float a = mn * __builtin_amdgcn_rcpf(fmaxf(mx, 1e-30f));
    const float s = a * a;
    float r = a * (0.99997726f + s * (-0.33262347f + s * (0.19354346f +
              s * (-0.11643287f + s * (0.05265332f - s * 0.01172120f)))));
    if (ay > ax) r = 1.5707963268f - r;
    if (x < 0.0f) r = 3.1415926536f - r;
    r = (y < 0.0f) ? -r : r;
    return r * 0.15915494309189535f;
}

// acos(x), |err| <= 6.8e-5 rad
__device__ __forceinline__ float fast_acos(float x) {
    const float ax = __builtin_fabsf(x);
    const float t = __builtin_amdgcn_sqrtf(1.0f - ax);
    const float p = t * (1.5707288f + ax * (-0.2121144f +
                    ax * (0.0742610f - ax * 0.0187293f)));
    return (x < 0.0f) ? (3.1415926536f - p) : p;
}

// one-blob: out[i]=exp(-8(x-c_i)^2) via exp ladder (2 transcendentals)
__device__ __forceinline__ void blob4(float x, float* out) {
    const float dx = x - 0.125f;
    const float E0 = __expf(-8.0f * dx * dx);
    const float R  = __expf(4.0f * dx);
    const float t1 = R * 0.60653066f;
    const float t2 = R * 0.22313016f;
    const float t3 = R * 0.082084999f;
    out[0] = E0;
    out[1] = E0 * t1;
    out[2] = out[1] * t2;
    out[3] = out[2] * t3;
}

// compute packed-weight chunk c (= unit*64 + lane2) from the f32 weights
__device__ __forceinline__ f16x8 make_wchunk(
    int c, const float* __restrict__ W0, const float* __restrict__ W1,
    const float* __restrict__ W2, const float* __restrict__ W3,
    const float* __restrict__ W4, const float* __restrict__ W5,
    const float* __restrict__ W6)
{
    const int lane2 = c & 63;
    const int unit  = c >> 6;
    const int q = lane2 >> 4, m = lane2 & 15;
    f16x8 v;
    if (unit < 48) {
        const int l = unit >> 3, kt = (unit & 7) >> 2, mt = unit & 3;
        const float* Ws[6] = {W0, W1, W2, W3, W4, W5};
        const float* __restrict__ Wl = Ws[l];
#pragma unroll
        for (int j = 0; j < 8; ++j) {
            const int x = kt * 32 + q * 8 + j;
            const int src = (l == 0) ? x : tau(x);
            v[j] = (f16)Wl[(mt * 16 + m) * 64 + src];
        }
    } else {
        const int kt = unit - 48;
#pragma unroll
        for (int j = 0; j < 8; ++j) {
            const int src = tau(kt * 32 + q * 8 + j);
            v[j] = (m < 3) ? (f16)W6[m * 64 + src] : (f16)0.0f;
        }
    }
    return v;
}

__global__ __launch_bounds__(256, 1) void pack_weights_kernel(
    const float* __restrict__ W0, const float* __restrict__ W1,
    const float* __restrict__ W2, const float* __restrict__ W3,
    const float* __restrict__ W4, const float* __restrict__ W5,
    const float* __restrict__ W6, f16* __restrict__ ws)
{
    const int c = (int)blockIdx.x * 256 + threadIdx.x;
    if (c >= WCHUNKS) return;
    *(f16x8*)(ws + (size_t)c * 8) = make_wchunk(c, W0, W1, W2, W3, W4, W5, W6);
}

// async global->LDS DMA, 16B per lane. LDS dest is linear per wave:
// HW uses wave-uniform base + lane*16 (guide §5; m97/m104 semantics),
// which matches our chunk layout exactly.
__device__ __forceinline__ void async_ld16(const void* g, void* l) {
    __builtin_amdgcn_global_load_lds(
        (const __attribute__((address_space(1))) void*)g,
        (__attribute__((address_space(3))) void*)l,
        16, 0, 0);
}

template<int PACKED>
__global__ __launch_bounds__(BLOCK, 4) void nrc_mlp_kernel(
    const float* __restrict__ P,  const float* __restrict__ WI,
    const float* __restrict__ NV, const float* __restrict__ AL,
    const float* __restrict__ BE, const float* __restrict__ RR,
    const f16*   __restrict__ ws,
    const float* __restrict__ W0, const float* __restrict__ W1,
    const float* __restrict__ W2, const float* __restrict__ W3,
    const float* __restrict__ W4, const float* __restrict__ W5,
    const float* __restrict__ W6, float* __restrict__ Out)
{
    // [0,51200): packed weight image (48 hidden units + 2 W6 units).
    // [51200,67584): staging, 4 x 4KB consumer slices.
    __shared__ __attribute__((aligned(16))) unsigned char smem[LDS_TOT];

    const int tid  = threadIdx.x;
    const int lane = tid & 63;
    const int w    = tid >> 6;
    const int q    = lane >> 4;
    const int m    = lane & 15;
    const bool producer = (w < 4);
    const int  cw  = w & 3;          // producer p pairs with consumer p
    const int  blk_base = (int)blockIdx.x * SPB;

    unsigned char* const stg = smem + LDS_WEI;

    // ---- weight image: async DMA (or VALU fallback), issued before encode,
    //      complete well before the first compute() (>= 2 barriers later) ----
    if (PACKED) {
#pragma unroll
        for (int i = 0; i < (WCHUNKS + BLOCK - 1) / BLOCK; ++i) {
            const int c = i * BLOCK + tid;
            if (c < WCHUNKS)
                async_ld16(ws + (size_t)c * 8, smem + c * 16);
        }
    } else {
#pragma unroll
        for (int i = 0; i < (WCHUNKS + BLOCK - 1) / BLOCK; ++i) {
            const int c = i * BLOCK + tid;
            if (c < WCHUNKS)
                *(f16x8*)(smem + c * 16) = make_wchunk(c, W0, W1, W2, W3, W4, W5, W6);
        }
    }

    const f16x4 zero4 = {(f16)0.0f, (f16)0.0f, (f16)0.0f, (f16)0.0f};
    const f32x4 ZF = {0.0f, 0.0f, 0.0f, 0.0f};
    unsigned char* const wb = smem + lane * 16;

    f16x8 bf[TILES][2];   // consumer: one round's B fragments

    // ---- consumer: 6 hidden layers + W6 + scaled store for round rr ----
    auto compute = [&](int rr) {
        __builtin_amdgcn_s_setprio(1);
#pragma unroll
        for (int layer = 0; layer < 6; ++layer) {
            f16x8 wa[8];   // frag index f = kt*4+mt
#pragma unroll
            for (int f = 0; f < 8; ++f)
                wa[f] = *(const f16x8*)(wb + (layer * 8 + f) * 1024);

#pragma unroll
            for (int t = 0; t < TILES; ++t) {
                f32x4 acc[4];
#pragma unroll
                for (int mt = 0; mt < 4; ++mt) {
                    f32x4 z = MFMA32(wa[mt], bf[t][0], ZF);
                    z = MFMA32(wa[4 + mt], bf[t][1], z);
                    acc[mt] = z;
                }
                f16x4 pk[4];
#pragma unroll
                for (int mt = 0; mt < 4; ++mt)
                    pk[mt] = __builtin_elementwise_max(pack4(acc[mt]), zero4);
                bf[t][0] = cat44(pk[0], pk[1]);   // tau absorbed in next layer
                bf[t][1] = cat44(pk[2], pk[3]);
            }
        }
        __builtin_amdgcn_s_setprio(0);
        // epilogue: W6 frags from LDS (wa dead here), alpha+beta preloaded
        const f16x8 w6f0 = *(const f16x8*)(wb + 48 * 1024);
        const f16x8 w6f1 = *(const f16x8*)(wb + 49 * 1024);
        const int rbase = blk_base + rr * 256 + cw * 64;
        float aa[TILES][3];
#pragma unroll
        for (int t = 0; t < TILES; ++t) {
            const int s = rbase + t * 16 + m;
#pragma unroll
            for (int d = 0; d < 3; ++d)
                aa[t][d] = AL[s * 3 + d] + BE[s * 3 + d];
        }
#pragma unroll
        for (int t = 0; t < TILES; ++t) {
            f32x4 z = MFMA32(w6f0, bf[t][0], ZF);
            z = MFMA32(w6f1, bf[t][1], z);
            if (lane < 16) {   // q==0: D rows r=0..2 = output channels, col m
                const int s = rbase + t * 16 + m;
                float* o = Out + s * 3;
                o[0] = z[0] * aa[t][0];
                o[1] = z[1] * aa[t][1];
                o[2] = z[2] * aa[t][2];
            }
        }
    };

    // ---- pipelined rounds: P encodes r while C computes r-1 ----
    for (int r = 0; r < ROUNDS; ++r) {
        f16x2 hf[32];   // producer: features of sample (lane), packed pairs
        if (producer) {
            const int s = blk_base + r * 256 + cw * 64 + lane;

            float pv[3], wv[3], nv[3], av[3], bv[3];
#pragma unroll
            for (int d = 0; d < 3; ++d) {
                pv[d] = P [s * 3 + d];
                wv[d] = WI[s * 3 + d];
                nv[d] = NV[s * 3 + d];
                av[d] = AL[s * 3 + d];
                bv[d] = BE[s * 3 + d];
            }
            const float rv = RR[s];

            // freq embed: base sin/cos at pi*p (revolutions) + angle doubling
#pragma unroll
            for (int d = 0; d < 3; ++d) {
                float sA[6], cA[6];
                const float fr = __builtin_amdgcn_fractf(pv[d] * 0.5f);
                sA[0] = __builtin_amdgcn_sinf(fr);
                cA[0] = __builtin_amdgcn_cosf(fr);
#pragma unroll
                for (int k = 1; k < 6; ++k) {
                    const float s2 = sA[k-1] * sA[k-1];
                    const float sc = sA[k-1] * cA[k-1];
                    cA[k] = fmaf(-2.0f, s2, 1.0f);
                    sA[k] = sc + sc;
                }
                hf[d * 6 + 0] = pkh(sA[0], sA[1]);
                hf[d * 6 + 1] = pkh(sA[2], sA[3]);
                hf[d * 6 + 2] = pkh(sA[4], sA[5]);
                hf[d * 6 + 3] = pkh(cA[0], cA[1]);
                hf[d * 6 + 4] = pkh(cA[2], cA[3]);
                hf[d * 6 + 5] = pkh(cA[4], cA[5]);
            }
#pragma unroll
            for (int which = 0; which < 2; ++which) {
                const float* dv = (which == 0) ? wv : nv;
                const int ho = 18 + which * 4;
                const float nr = __builtin_amdgcn_sqrtf(dv[0]*dv[0] + dv[1]*dv[1] + dv[2]*dv[2]) + 1e-8f;
                const float u  = fast_atan2_rev(dv[1], dv[0]) + 0.5f;
                float zc = dv[2] * __builtin_amdgcn_rcpf(nr);
                zc = fminf(fmaxf(zc, -1.0f + 1e-6f), 1.0f - 1e-6f);
                const float vv = fast_acos(zc) * 0.3183098861837907f;
                float ob[8];
                blob4(u,  &ob[0]);
                blob4(vv, &ob[4]);
                hf[ho + 0] = pkh(ob[0], ob[1]);
                hf[ho + 1] = pkh(ob[2], ob[3]);
                hf[ho + 2] = pkh(ob[4], ob[5]);
                hf[ho + 3] = pkh(ob[6], ob[7]);
            }
            {
                float ob[4];
                blob4(1.0f - __expf(-rv), ob);
                hf[26] = pkh(ob[0], ob[1]);
                hf[27] = pkh(ob[2], ob[3]);
            }
            hf[28] = pkh(av[0], av[1]);
            hf[29] = pkh(av[2], bv[0]);
            hf[30] = pkh(bv[1], bv[2]);
            hf[31] = pkh(1.0f, 1.0f);
        } else if (r > 0) {
            compute(r - 1);       // overlaps with producers' encode of round r
        }

        // ---- two half-exchanges (2 tiles each) through the staging region.
        // slice layout per consumer: within half h, region (lane>>4)&1 holds
        // one 16-sample tile; sample m at +m*128, chunk g at dword slot
        // (4g+4m)&31 -- byte-identical to the verified R15 staging format.
#pragma unroll
        for (int h = 0; h < 2; ++h) {
            __syncthreads();      // consumers done reading previous contents
            if (producer && ((lane >> 5) == h)) {   // 32 lanes stage 2 tiles
                unsigned char* const tb =
                    stg + cw * 4096 + ((lane >> 4) & 1) * 2048 + m * 128;
#pragma unroll
                for (int g = 0; g < 8; ++g) {
                    const int slot0 = (4 * g + 4 * m) & 31;
                    *(f16x8*)(tb + slot0 * 4) =
                        cat44(cat22(hf[g*4 + 0], hf[g*4 + 1]),
                              cat22(hf[g*4 + 2], hf[g*4 + 3]));
                }
            }
            __syncthreads();      // half staged
            if (!producer) {
#pragma unroll
                for (int t2 = 0; t2 < 2; ++t2) {
#pragma unroll
                    for (int kt = 0; kt < 2; ++kt) {
                        const int s0 = (16 * kt + 4 * q + 4 * m) & 31;
                        bf[h * 2 + t2][kt] = *(const f16x8*)(
                            stg + cw * 4096 + t2 * 2048 + m * 128 + s0 * 4);
                    }
                }
            }
        }
    }
    if (!producer) compute(ROUNDS - 1);   // drain the pipeline
}

extern "C" void kernel_launch(void* const* d_in, const int* in_sizes, int n_in,
                              void* d_out, int out_size, void* d_ws, size_t ws_size,
                              hipStream_t stream) {
    (void)n_in; (void)out_size;
    const float* P  = (const float*)d_in[0];
    const float* WI = (const float*)d_in[1];
    const float* NV = (const float*)d_in[2];
    const float* AL = (const float*)d_in[3];
    const float* BE = (const float*)d_in[4];
    const float* RR = (const float*)d_in[5];
    const float* W0 = (const float*)d_in[6];
    const float* W1 = (const float*)d_in[7];
    const float* W2 = (const float*)d_in[8];
    const float* W3 = (const float*)d_in[9];
    const float* W4 = (const float*)d_in[10];
    const float* W5 = (const float*)d_in[11];
    const float* W6 = (const float*)d_in[12];
    f16*   ws  = (f16*)d_ws;
    float* Out = (float*)d_out;

    const int Bn = in_sizes[0] / 3;     // 1,048,576
    const int grid = Bn / SPB;          // 512 blocks of 512 threads

    // ws_size fixed per session -> same path every call (graph-safe).
    if (ws_size >= WS_BYTES) {
        hipLaunchKernelGGL(pack_weights_kernel, dim3((WCHUNKS + 255) / 256),
                           dim3(256), 0, stream, W0, W1, W2, W3, W4, W5, W6, ws);
        hipLaunchKernelGGL((nrc_mlp_kernel<1>), dim3(grid), dim3(BLOCK), 0, stream,
                           P, WI, NV, AL, BE, RR, ws,
                           W0, W1, W2, W3, W4, W5, W6, Out);
    } else {
        hipLaunchKernelGGL((nrc_mlp_kernel<0>), dim3(grid), dim3(BLOCK), 0, stream,
                           P, WI, NV, AL, BE, RR, ws,
                           W0, W1, W2, W3, W4, W5, W6, Out);
    }
}

// Round 5
// 179.501 us; speedup vs baseline: 1.0815x; 1.0006x over previous
//
#include <hip/hip_runtime.h>

// NRC fused encode + 7-layer W=64 MLP. R18 = R17 with the pipeline ROTATED to
// kill the last register-pressure spill.
//
// R17 post-mortem: WRITE 66.7MB (output=12.6) -> ~54MB scratch spills remain.
// Liveness: in the order [encode(r) || compute(r-1)] -> stage -> read, bf(32)
// flows from iter r-1's read THROUGH the producer's encode block (producer
// path has no redef) into compute at iter-r top => encode-region pressure
// hf32+bf32+temps ~ 110 > 128-cap comfort. R18 rotation:
//   [P: encode(r)] -> barA -> [P: write slice] -> barB -> [C: read + compute(r)]
// with the backedge taking P into encode(r+1) while C runs compute(r):
// SAME steady-state overlap (encode || compute), but bf is dead through
// encode and hf is dead through compute. Producer peak ~70, consumer ~98
// (= R15's measured-fitting envelope). No LDS/format changes vs R17.
//
// Structure: 8 waves/block = 4 producers (encode, VALU) + 4 consumers (MLP,
// MFMA). Waves round-robin to SIMDs -> each SIMD holds P and C waves from
// each resident block -> VALU and MFMA pipes fed concurrently (m114 overlap).
//
// 16x16x32 f16 fragment maps (verified):
//   A[m=lane&15][k=(lane>>4)*8+j], B[k=(lane>>4)*8+j][n=lane&15],
//   D[row=(lane>>4)*4+r][col=lane&15]  (4 blocks mt: row=mt*16+q*4+r)
// Chaining: bf[kt]=concat(relu(pack(acc[2kt])), relu(pack(acc[2kt+1])));
// k-index mismatch absorbed by permuting W1..W5,W6 columns with
// tau(x)=32(x>>5)+16((x&7)>>2)+4((x>>3)&3)+(x&3) at pack time.

typedef _Float16 f16;
typedef f16 f16x2 __attribute__((ext_vector_type(2)));
typedef f16 f16x4 __attribute__((ext_vector_type(4)));
typedef f16 f16x8 __attribute__((ext_vector_type(8)));
typedef float f32x4 __attribute__((ext_vector_type(4)));

#define MFMA32(A, B, C) __builtin_amdgcn_mfma_f32_16x16x32_f16(A, B, C, 0, 0, 0)

static constexpr int TILES  = 4;        // 16-sample tiles per consumer round
static constexpr int WAVES  = 8;        // 4 producers + 4 consumers
static constexpr int BLOCK  = WAVES * 64;    // 512
static constexpr int ROUNDS = 8;
static constexpr int SPB    = ROUNDS * 4 * 64;   // 2048 samples per block

static constexpr int    WUNITS   = 50;      // 48 hidden frag-units + 2 W6
static constexpr int    WCHUNKS  = WUNITS * 64;           // 3200 x 16B
static constexpr size_t WS_BYTES = (size_t)WCHUNKS * 16;  // 51200
static constexpr int    LDS_WEI  = WUNITS * 1024;         // 51200
static constexpr int    LDS_STG  = 4 * 4096;              // 16384
static constexpr int    LDS_TOT  = LDS_WEI + LDS_STG;     // 67584

__host__ __device__ __forceinline__ int tau(int x) {
    return (x & 32) + ((x & 7) >> 2) * 16 + ((x >> 3) & 3) * 4 + (x & 3);
}

__device__ __forceinline__ f16x2 pkh(float a, float b) {
    return __builtin_bit_cast(f16x2, __builtin_amdgcn_cvt_pkrtz(a, b));
}

__device__ __forceinline__ f16x4 cat22(f16x2 a, f16x2 b) {
    return __builtin_shufflevector(a, b, 0, 1, 2, 3);
}

__device__ __forceinline__ f16x8 cat44(f16x4 a, f16x4 b) {
    return __builtin_shufflevector(a, b, 0, 1, 2, 3, 4, 5, 6, 7);
}

__device__ __forceinline__ f16x4 pack4(f32x4 v) {
    return cat22(pkh(v[0], v[1]), pkh(v[2], v[3]));
}

// atan2(y,x) / (2*pi)
__device__ __forceinline__ float fast_atan2_rev(float y, float x) {
    const float ax = __builtin_fabsf(x), ay = __builtin_fabsf(y);
    const float mx = fmaxf(ax, ay), mn = fminf(ax, ay);
    const float a = mn * __builtin_amdgcn_rcpf(fmaxf(mx, 1e-30f));
    const float s = a * a;
    float r = a * (0.99997726f + s * (-0.33262347f + s * (0.19354346f +
              s * (-0.11643287f + s * (0.05265332f - s * 0.01172120f)))));
    if (ay > ax) r = 1.5707963268f - r;
    if (x < 0.0f) r = 3.1415926536f - r;
    r = (y < 0.0f) ? -r : r;
    return r * 0.15915494309189535f;
}

// acos(x), |err| <= 6.8e-5 rad
__device__ __forceinline__ float fast_acos(float x) {
    const float ax = __builtin_fabsf(x);
    const float t = __builtin_amdgcn_sqrtf(1.0f - ax);
    const float p = t * (1.5707288f + ax * (-0.2121144f +
                    ax * (0.0742610f - ax * 0.0187293f)));
    return (x < 0.0f) ? (3.1415926536f - p) : p;
}

// one-blob: out[i]=exp(-8(x-c_i)^2) via exp ladder (2 transcendentals)
__device__ __forceinline__ void blob4(float x, float* out) {
    const float dx = x - 0.125f;
    const float E0 = __expf(-8.0f * dx * dx);
    const float R  = __expf(4.0f * dx);
    const float t1 = R * 0.60653066f;
    const float t2 = R * 0.22313016f;
    const float t3 = R * 0.082084999f;
    out[0] = E0;
    out[1] = E0 * t1;
    out[2] = out[1] * t2;
    out[3] = out[2] * t3;
}

// compute packed-weight chunk c (= unit*64 + lane2) from the f32 weights
__device__ __forceinline__ f16x8 make_wchunk(
    int c, const float* __restrict__ W0, const float* __restrict__ W1,
    const float* __restrict__ W2, const float* __restrict__ W3,
    const float* __restrict__ W4, const float* __restrict__ W5,
    const float* __restrict__ W6)
{
    const int lane2 = c & 63;
    const int unit  = c >> 6;
    const int q = lane2 >> 4, m = lane2 & 15;
    f16x8 v;
    if (unit < 48) {
        const int l = unit >> 3, kt = (unit & 7) >> 2, mt = unit & 3;
        const float* Ws[6] = {W0, W1, W2, W3, W4, W5};
        const float* __restrict__ Wl = Ws[l];
#pragma unroll
        for (int j = 0; j < 8; ++j) {
            const int x = kt * 32 + q * 8 + j;
            const int src = (l == 0) ? x : tau(x);
            v[j] = (f16)Wl[(mt * 16 + m) * 64 + src];
        }
    } else {
        const int kt = unit - 48;
#pragma unroll
        for (int j = 0; j < 8; ++j) {
            const int src = tau(kt * 32 + q * 8 + j);
            v[j] = (m < 3) ? (f16)W6[m * 64 + src] : (f16)0.0f;
        }
    }
    return v;
}

__global__ __launch_bounds__(256, 1) void pack_weights_kernel(
    const float* __restrict__ W0, const float* __restrict__ W1,
    const float* __restrict__ W2, const float* __restrict__ W3,
    const float* __restrict__ W4, const float* __restrict__ W5,
    const float* __restrict__ W6, f16* __restrict__ ws)
{
    const int c = (int)blockIdx.x * 256 + threadIdx.x;
    if (c >= WCHUNKS) return;
    *(f16x8*)(ws + (size_t)c * 8) = make_wchunk(c, W0, W1, W2, W3, W4, W5, W6);
}

// async global->LDS DMA, 16B per lane. LDS dest is linear per wave:
// HW uses wave-uniform base + lane*16 (guide §5; m97/m104 semantics),
// which matches our chunk layout exactly.
__device__ __forceinline__ void async_ld16(const void* g, void* l) {
    __builtin_amdgcn_global_load_lds(
        (const __attribute__((address_space(1))) void*)g,
        (__attribute__((address_space(3))) void*)l,
        16, 0, 0);
}

template<int PACKED>
__global__ __launch_bounds__(BLOCK, 4) void nrc_mlp_kernel(
    const float* __restrict__ P,  const float* __restrict__ WI,
    const float* __restrict__ NV, const float* __restrict__ AL,
    const float* __restrict__ BE, const float* __restrict__ RR,
    const f16*   __restrict__ ws,
    const float* __restrict__ W0, const float* __restrict__ W1,
    const float* __restrict__ W2, const float* __restrict__ W3,
    const float* __restrict__ W4, const float* __restrict__ W5,
    const float* __restrict__ W6, float* __restrict__ Out)
{
    // [0,51200): packed weight image (48 hidden units + 2 W6 units).
    // [51200,67584): staging, 4 x 4KB consumer slices (2 tiles live at a time).
    __shared__ __attribute__((aligned(16))) unsigned char smem[LDS_TOT];

    const int tid  = threadIdx.x;
    const int lane = tid & 63;
    const int w    = tid >> 6;
    const int q    = lane >> 4;
    const int m    = lane & 15;
    const bool producer = (w < 4);
    const int  cw  = w & 3;          // producer p pairs with consumer p
    const int  blk_base = (int)blockIdx.x * SPB;

    unsigned char* const stg = smem + LDS_WEI;

    // ---- weight image: async DMA (or VALU fallback), issued before encode,
    //      complete well before the first compute() (>= 2 barriers later) ----
    if (PACKED) {
#pragma unroll
        for (int i = 0; i < (WCHUNKS + BLOCK - 1) / BLOCK; ++i) {
            const int c = i * BLOCK + tid;
            if (c < WCHUNKS)
                async_ld16(ws + (size_t)c * 8, smem + c * 16);
        }
    } else {
#pragma unroll
        for (int i = 0; i < (WCHUNKS + BLOCK - 1) / BLOCK; ++i) {
            const int c = i * BLOCK + tid;
            if (c < WCHUNKS)
                *(f16x8*)(smem + c * 16) = make_wchunk(c, W0, W1, W2, W3, W4, W5, W6);
        }
    }

    const f16x4 zero4 = {(f16)0.0f, (f16)0.0f, (f16)0.0f, (f16)0.0f};
    const f32x4 ZF = {0.0f, 0.0f, 0.0f, 0.0f};
    unsigned char* const wb = smem + lane * 16;

    // ---- pipelined rounds: after the staging exchange of round r, consumers
    // compute(r) while producers flow through the backedge into encode(r+1).
    for (int r = 0; r < ROUNDS; ++r) {
        f16x2 hf[32];   // producer: features of sample (lane), packed pairs
        if (producer) {
            const int s = blk_base + r * 256 + cw * 64 + lane;

            float pv[3], wv[3], nv[3], av[3], bv[3];
#pragma unroll
            for (int d = 0; d < 3; ++d) {
                pv[d] = P [s * 3 + d];
                wv[d] = WI[s * 3 + d];
                nv[d] = NV[s * 3 + d];
                av[d] = AL[s * 3 + d];
                bv[d] = BE[s * 3 + d];
            }
            const float rv = RR[s];

            // freq embed: base sin/cos at pi*p (revolutions) + angle doubling
#pragma unroll
            for (int d = 0; d < 3; ++d) {
                float sA[6], cA[6];
                const float fr = __builtin_amdgcn_fractf(pv[d] * 0.5f);
                sA[0] = __builtin_amdgcn_sinf(fr);
                cA[0] = __builtin_amdgcn_cosf(fr);
#pragma unroll
                for (int k = 1; k < 6; ++k) {
                    const float s2 = sA[k-1] * sA[k-1];
                    const float sc = sA[k-1] * cA[k-1];
                    cA[k] = fmaf(-2.0f, s2, 1.0f);
                    sA[k] = sc + sc;
                }
                hf[d * 6 + 0] = pkh(sA[0], sA[1]);
                hf[d * 6 + 1] = pkh(sA[2], sA[3]);
                hf[d * 6 + 2] = pkh(sA[4], sA[5]);
                hf[d * 6 + 3] = pkh(cA[0], cA[1]);
                hf[d * 6 + 4] = pkh(cA[2], cA[3]);
                hf[d * 6 + 5] = pkh(cA[4], cA[5]);
            }
#pragma unroll
            for (int which = 0; which < 2; ++which) {
                const float* dv = (which == 0) ? wv : nv;
                const int ho = 18 + which * 4;
                const float nr = __builtin_amdgcn_sqrtf(dv[0]*dv[0] + dv[1]*dv[1] + dv[2]*dv[2]) + 1e-8f;
                const float u  = fast_atan2_rev(dv[1], dv[0]) + 0.5f;
                float zc = dv[2] * __builtin_amdgcn_rcpf(nr);
                zc = fminf(fmaxf(zc, -1.0f + 1e-6f), 1.0f - 1e-6f);
                const float vv = fast_acos(zc) * 0.3183098861837907f;
                float ob[8];
                blob4(u,  &ob[0]);
                blob4(vv, &ob[4]);
                hf[ho + 0] = pkh(ob[0], ob[1]);
                hf[ho + 1] = pkh(ob[2], ob[3]);
                hf[ho + 2] = pkh(ob[4], ob[5]);
                hf[ho + 3] = pkh(ob[6], ob[7]);
            }
            {
                float ob[4];
                blob4(1.0f - __expf(-rv), ob);
                hf[26] = pkh(ob[0], ob[1]);
                hf[27] = pkh(ob[2], ob[3]);
            }
            hf[28] = pkh(av[0], av[1]);
            hf[29] = pkh(av[2], bv[0]);
            hf[30] = pkh(bv[1], bv[2]);
            hf[31] = pkh(1.0f, 1.0f);
        }

        // ---- two half-exchanges (2 tiles each) through the staging region.
        // slice layout per consumer: within half h, region (lane>>4)&1 holds
        // one 16-sample tile; sample m at +m*128, chunk g at dword slot
        // (4g+4m)&31 -- byte-identical to the verified R15/R17 staging format.
        f16x8 bf[TILES][2];   // consumer: this round's B fragments
#pragma unroll
        for (int h = 0; h < 2; ++h) {
            __syncthreads();      // consumers done reading previous contents
            if (producer && ((lane >> 5) == h)) {   // 32 lanes stage 2 tiles
                unsigned char* const tb =
                    stg + cw * 4096 + ((lane >> 4) & 1) * 2048 + m * 128;
#pragma unroll
                for (int g = 0; g < 8; ++g) {
                    const int slot0 = (4 * g + 4 * m) & 31;
                    *(f16x8*)(tb + slot0 * 4) =
                        cat44(cat22(hf[g*4 + 0], hf[g*4 + 1]),
                              cat22(hf[g*4 + 2], hf[g*4 + 3]));
                }
            }
            __syncthreads();      // half staged
            if (!producer) {
#pragma unroll
                for (int t2 = 0; t2 < 2; ++t2) {
#pragma unroll
                    for (int kt = 0; kt < 2; ++kt) {
                        const int s0 = (16 * kt + 4 * q + 4 * m) & 31;
                        bf[h * 2 + t2][kt] = *(const f16x8*)(
                            stg + cw * 4096 + t2 * 2048 + m * 128 + s0 * 4);
                    }
                }
            }
        }

        // ---- consumer: compute round r NOW (overlaps producers' encode of
        // round r+1 via the backedge; next barrier is iter r+1's barrier A,
        // which producers reach only after finishing encode(r+1)) ----
        if (!producer) {
            __builtin_amdgcn_s_setprio(1);
#pragma unroll
            for (int layer = 0; layer < 6; ++layer) {
                f16x8 wa[8];   // frag index f = kt*4+mt
#pragma unroll
                for (int f = 0; f < 8; ++f)
                    wa[f] = *(const f16x8*)(wb + (layer * 8 + f) * 1024);

#pragma unroll
                for (int t = 0; t < TILES; ++t) {
                    f32x4 acc[4];
#pragma unroll
                    for (int mt = 0; mt < 4; ++mt) {
                        f32x4 z = MFMA32(wa[mt], bf[t][0], ZF);
                        z = MFMA32(wa[4 + mt], bf[t][1], z);
                        acc[mt] = z;
                    }
                    f16x4 pk[4];
#pragma unroll
                    for (int mt = 0; mt < 4; ++mt)
                        pk[mt] = __builtin_elementwise_max(pack4(acc[mt]), zero4);
                    bf[t][0] = cat44(pk[0], pk[1]);   // tau absorbed next layer
                    bf[t][1] = cat44(pk[2], pk[3]);
                }
            }
            __builtin_amdgcn_s_setprio(0);
            // epilogue: W6 frags from LDS (wa dead), alpha+beta from global
            const f16x8 w6f0 = *(const f16x8*)(wb + 48 * 1024);
            const f16x8 w6f1 = *(const f16x8*)(wb + 49 * 1024);
            const int rbase = blk_base + r * 256 + cw * 64;
            float aa[TILES][3];
#pragma unroll
            for (int t = 0; t < TILES; ++t) {
                const int s = rbase + t * 16 + m;
#pragma unroll
                for (int d = 0; d < 3; ++d)
                    aa[t][d] = AL[s * 3 + d] + BE[s * 3 + d];
            }
#pragma unroll
            for (int t = 0; t < TILES; ++t) {
                f32x4 z = MFMA32(w6f0, bf[t][0], ZF);
                z = MFMA32(w6f1, bf[t][1], z);
                if (lane < 16) {   // q==0: D rows r=0..2 = out channels, col m
                    const int s = rbase + t * 16 + m;
                    float* o = Out + s * 3;
                    o[0] = z[0] * aa[t][0];
                    o[1] = z[1] * aa[t][1];
                    o[2] = z[2] * aa[t][2];
                }
            }
        }
    }
}

extern "C" void kernel_launch(void* const* d_in, const int* in_sizes, int n_in,
                              void* d_out, int out_size, void* d_ws, size_t ws_size,
                              hipStream_t stream) {
    (void)n_in; (void)out_size;
    const float* P  = (const float*)d_in[0];
    const float* WI = (const float*)d_in[1];
    const float* NV = (const float*)d_in[2];
    const float* AL = (const float*)d_in[3];
    const float* BE = (const float*)d_in[4];
    const float* RR = (const float*)d_in[5];
    const float* W0 = (const float*)d_in[6];
    const float* W1 = (const float*)d_in[7];
    const float* W2 = (const float*)d_in[8];
    const float* W3 = (const float*)d_in[9];
    const float* W4 = (const float*)d_in[10];
    const float* W5 = (const float*)d_in[11];
    const float* W6 = (const float*)d_in[12];
    f16*   ws  = (f16*)d_ws;
    float* Out = (float*)d_out;

    const int Bn = in_sizes[0] / 3;     // 1,048,576
    const int grid = Bn / SPB;          // 512 blocks of 512 threads

    // ws_size fixed per session -> same path every call (graph-safe).
    if (ws_size >= WS_BYTES) {
        hipLaunchKernelGGL(pack_weights_kernel, dim3((WCHUNKS + 255) / 256),
                           dim3(256), 0, stream, W0, W1, W2, W3, W4, W5, W6, ws);
        hipLaunchKernelGGL((nrc_mlp_kernel<1>), dim3(grid), dim3(BLOCK), 0, stream,
                           P, WI, NV, AL, BE, RR, ws,
                           W0, W1, W2, W3, W4, W5, W6, Out);
    } else {
        hipLaunchKernelGGL((nrc_mlp_kernel<0>), dim3(grid), dim3(BLOCK), 0, stream,
                           P, WI, NV, AL, BE, RR, ws,
                           W0, W1, W2, W3, W4, W5, W6, Out);
    }
}

// Round 6
// 177.110 us; speedup vs baseline: 1.0961x; 1.0135x over previous
//
#include <hip/hip_runtime.h>

// NRC fused encode + 7-layer W=64 MLP. R19 = producer/consumer waves in the
// BIG-REGISTER regime.
//
// R17/R18 post-mortem: ~54MB scratch spills persisted through two liveness
// restructurings. Root cause: at (512,4) the unified budget is 128 regs/wave
// and the allocator pins 64 arch VGPRs; ANY hf/bf union pressure spills.
// The 8-wave fused P+C body structurally does not fit 128 regs.
// R19: BLOCK=256 = 2 P-waves + 2 C-waves, __launch_bounds__(256,2), LDS
// 67584 -> 2 blocks/CU = 8 waves/CU = 2 waves/SIMD = 256 regs/wave.
//   - every SIMD holds exactly 1 P + 1 C wave -> VALU & MFMA pipes fed
//     concurrently by construction (m114 overlap).
//   - consumer peak ~120 regs, producer ~75: no spills possible.
//   - matrix pipe: 1 MFMA issue / ~19cy / SIMD needed; one C wave with 4
//     independent mt-chains sustains it (bubbles only at layer boundaries).
//   - ROUNDS=16, SPB=2048, grid=512 = exactly one resident generation.
//   - round: [P encode(r) || C compute(r-1)] -> bar -> P write 8KB slice
//     -> bar -> backedge. Single-buffered slices, 2 barriers/round.
//   - aa(alpha+beta) prefetched before the layer chain (latency hidden).
//
// 16x16x32 f16 fragment maps (verified):
//   A[m=lane&15][k=(lane>>4)*8+j], B[k=(lane>>4)*8+j][n=lane&15],
//   D[row=(lane>>4)*4+r][col=lane&15]  (4 blocks mt: row=mt*16+q*4+r)
// Chaining: bf[kt]=concat(relu(pack(acc[2kt])), relu(pack(acc[2kt+1])));
// k-index mismatch absorbed by permuting W1..W5,W6 columns with
// tau(x)=32(x>>5)+16((x&7)>>2)+4((x>>3)&3)+(x&3) at pack time.
// Staging tile format byte-identical to R15's verified layout
// (2KB per 16-sample tile; sample m at +m*128, chunk g at dword (4g+4m)&31).

typedef _Float16 f16;
typedef f16 f16x2 __attribute__((ext_vector_type(2)));
typedef f16 f16x4 __attribute__((ext_vector_type(4)));
typedef f16 f16x8 __attribute__((ext_vector_type(8)));
typedef float f32x4 __attribute__((ext_vector_type(4)));

#define MFMA32(A, B, C) __builtin_amdgcn_mfma_f32_16x16x32_f16(A, B, C, 0, 0, 0)

static constexpr int TILES  = 4;        // 16-sample tiles per pair per round
static constexpr int WAVES  = 4;        // 2 producers + 2 consumers
static constexpr int BLOCK  = WAVES * 64;    // 256
static constexpr int PAIRS  = 2;
static constexpr int ROUNDS = 16;
static constexpr int SPB    = ROUNDS * PAIRS * 64;   // 2048 samples per block

static constexpr int    WUNITS   = 50;      // 48 hidden frag-units + 2 W6
static constexpr int    WCHUNKS  = WUNITS * 64;           // 3200 x 16B
static constexpr size_t WS_BYTES = (size_t)WCHUNKS * 16;  // 51200
static constexpr int    LDS_WEI  = WUNITS * 1024;         // 51200
static constexpr int    LDS_STG  = PAIRS * 8192;          // 16384
static constexpr int    LDS_TOT  = LDS_WEI + LDS_STG;     // 67584

__host__ __device__ __forceinline__ int tau(int x) {
    return (x & 32) + ((x & 7) >> 2) * 16 + ((x >> 3) & 3) * 4 + (x & 3);
}

__device__ __forceinline__ f16x2 pkh(float a, float b) {
    return __builtin_bit_cast(f16x2, __builtin_amdgcn_cvt_pkrtz(a, b));
}

__device__ __forceinline__ f16x4 cat22(f16x2 a, f16x2 b) {
    return __builtin_shufflevector(a, b, 0, 1, 2, 3);
}

__device__ __forceinline__ f16x8 cat44(f16x4 a, f16x4 b) {
    return __builtin_shufflevector(a, b, 0, 1, 2, 3, 4, 5, 6, 7);
}

__device__ __forceinline__ f16x4 pack4(f32x4 v) {
    return cat22(pkh(v[0], v[1]), pkh(v[2], v[3]));
}

// atan2(y,x) / (2*pi)
__device__ __forceinline__ float fast_atan2_rev(float y, float x) {
    const float ax = __builtin_fabsf(x), ay = __builtin_fabsf(y);
    const float mx = fmaxf(ax, ay), mn = fminf(ax, ay);
    const float a = mn * __builtin_amdgcn_rcpf(fmaxf(mx, 1e-30f));
    const float s = a * a;
    float r = a * (0.99997726f + s * (-0.33262347f + s * (0.19354346f +
              s * (-0.11643287f + s * (0.05265332f - s * 0.01172120f)))));
    if (ay > ax) r = 1.5707963268f - r;
    if (x < 0.0f) r = 3.1415926536f - r;
    r = (y < 0.0f) ? -r : r;
    return r * 0.15915494309189535f;
}

// acos(x), |err| <= 6.8e-5 rad
__device__ __forceinline__ float fast_acos(float x) {
    const float ax = __builtin_fabsf(x);
    const float t = __builtin_amdgcn_sqrtf(1.0f - ax);
    const float p = t * (1.5707288f + ax * (-0.2121144f +
                    ax * (0.0742610f - ax * 0.0187293f)));
    return (x < 0.0f) ? (3.1415926536f - p) : p;
}

// one-blob: out[i]=exp(-8(x-c_i)^2) via exp ladder (2 transcendentals)
__device__ __forceinline__ void blob4(float x, float* out) {
    const float dx = x - 0.125f;
    const float E0 = __expf(-8.0f * dx * dx);
    const float R  = __expf(4.0f * dx);
    const float t1 = R * 0.60653066f;
    const float t2 = R * 0.22313016f;
    const float t3 = R * 0.082084999f;
    out[0] = E0;
    out[1] = E0 * t1;
    out[2] = out[1] * t2;
    out[3] = out[2] * t3;
}

// compute packed-weight chunk c (= unit*64 + lane2) from the f32 weights
__device__ __forceinline__ f16x8 make_wchunk(
    int c, const float* __restrict__ W0, const float* __restrict__ W1,
    const float* __restrict__ W2, const float* __restrict__ W3,
    const float* __restrict__ W4, const float* __restrict__ W5,
    const float* __restrict__ W6)
{
    const int lane2 = c & 63;
    const int unit  = c >> 6;
    const int q = lane2 >> 4, m = lane2 & 15;
    f16x8 v;
    if (unit < 48) {
        const int l = unit >> 3, kt = (unit & 7) >> 2, mt = unit & 3;
        const float* Ws[6] = {W0, W1, W2, W3, W4, W5};
        const float* __restrict__ Wl = Ws[l];
#pragma unroll
        for (int j = 0; j < 8; ++j) {
            const int x = kt * 32 + q * 8 + j;
            const int src = (l == 0) ? x : tau(x);
            v[j] = (f16)Wl[(mt * 16 + m) * 64 + src];
        }
    } else {
        const int kt = unit - 48;
#pragma unroll
        for (int j = 0; j < 8; ++j) {
            const int src = tau(kt * 32 + q * 8 + j);
            v[j] = (m < 3) ? (f16)W6[m * 64 + src] : (f16)0.0f;
        }
    }
    return v;
}

__global__ __launch_bounds__(256, 1) void pack_weights_kernel(
    const float* __restrict__ W0, const float* __restrict__ W1,
    const float* __restrict__ W2, const float* __restrict__ W3,
    const float* __restrict__ W4, const float* __restrict__ W5,
    const float* __restrict__ W6, f16* __restrict__ ws)
{
    const int c = (int)blockIdx.x * 256 + threadIdx.x;
    if (c >= WCHUNKS) return;
    *(f16x8*)(ws + (size_t)c * 8) = make_wchunk(c, W0, W1, W2, W3, W4, W5, W6);
}

// async global->LDS DMA, 16B per lane. LDS dest is linear per wave:
// HW uses wave-uniform base + lane*16 (guide §5; m97/m104 semantics),
// which matches our chunk layout exactly.
__device__ __forceinline__ void async_ld16(const void* g, void* l) {
    __builtin_amdgcn_global_load_lds(
        (const __attribute__((address_space(1))) void*)g,
        (__attribute__((address_space(3))) void*)l,
        16, 0, 0);
}

template<int PACKED>
__global__ __launch_bounds__(BLOCK, 2) void nrc_mlp_kernel(
    const float* __restrict__ P,  const float* __restrict__ WI,
    const float* __restrict__ NV, const float* __restrict__ AL,
    const float* __restrict__ BE, const float* __restrict__ RR,
    const f16*   __restrict__ ws,
    const float* __restrict__ W0, const float* __restrict__ W1,
    const float* __restrict__ W2, const float* __restrict__ W3,
    const float* __restrict__ W4, const float* __restrict__ W5,
    const float* __restrict__ W6, float* __restrict__ Out)
{
    // [0,51200): packed weight image (48 hidden units + 2 W6 units).
    // [51200,67584): staging, 2 x 8KB pair slices (4 tiles x 2KB each).
    __shared__ __attribute__((aligned(16))) unsigned char smem[LDS_TOT];

    const int tid  = threadIdx.x;
    const int lane = tid & 63;
    const int w    = tid >> 6;
    const int q    = lane >> 4;
    const int m    = lane & 15;
    const bool producer = (w < PAIRS);
    const int  pr  = producer ? w : (w - PAIRS);   // pair index
    const int  blk_base = (int)blockIdx.x * SPB;

    unsigned char* const stg = smem + LDS_WEI + pr * 8192;

    // ---- weight image: async DMA (or VALU fallback), issued at kernel
    //      start; drained by every wave's wait at the first barrier ----
    if (PACKED) {
#pragma unroll
        for (int i = 0; i < (WCHUNKS + BLOCK - 1) / BLOCK; ++i) {
            const int c = i * BLOCK + tid;
            if (c < WCHUNKS)
                async_ld16(ws + (size_t)c * 8, smem + c * 16);
        }
    } else {
#pragma unroll
        for (int i = 0; i < (WCHUNKS + BLOCK - 1) / BLOCK; ++i) {
            const int c = i * BLOCK + tid;
            if (c < WCHUNKS)
                *(f16x8*)(smem + c * 16) = make_wchunk(c, W0, W1, W2, W3, W4, W5, W6);
        }
    }

    const f16x4 zero4 = {(f16)0.0f, (f16)0.0f, (f16)0.0f, (f16)0.0f};
    const f32x4 ZF = {0.0f, 0.0f, 0.0f, 0.0f};
    unsigned char* const wb = smem + lane * 16;

    // Window w_r: [P: encode(r)] || [C: compute(r-1)]; then barA, P writes
    // slice(r), barB. C's compute(r) happens in window w_{r+1} via backedge.
    for (int r = 0; r < ROUNDS; ++r) {
        f16x2 hf[32];   // producer: features of sample (lane), packed pairs
        if (producer) {
            // ---------------- encode round r (64 samples/wave) -----------
            const int s = blk_base + r * (PAIRS * 64) + pr * 64 + lane;

            float pv[3], wv[3], nv[3], av[3], bv[3];
#pragma unroll
            for (int d = 0; d < 3; ++d) {
                pv[d] = P [s * 3 + d];
                wv[d] = WI[s * 3 + d];
                nv[d] = NV[s * 3 + d];
                av[d] = AL[s * 3 + d];
                bv[d] = BE[s * 3 + d];
            }
            const float rv = RR[s];

            // freq embed: base sin/cos at pi*p (revolutions) + angle doubling
#pragma unroll
            for (int d = 0; d < 3; ++d) {
                float sA[6], cA[6];
                const float fr = __builtin_amdgcn_fractf(pv[d] * 0.5f);
                sA[0] = __builtin_amdgcn_sinf(fr);
                cA[0] = __builtin_amdgcn_cosf(fr);
#pragma unroll
                for (int k = 1; k < 6; ++k) {
                    const float s2 = sA[k-1] * sA[k-1];
                    const float sc = sA[k-1] * cA[k-1];
                    cA[k] = fmaf(-2.0f, s2, 1.0f);
                    sA[k] = sc + sc;
                }
                hf[d * 6 + 0] = pkh(sA[0], sA[1]);
                hf[d * 6 + 1] = pkh(sA[2], sA[3]);
                hf[d * 6 + 2] = pkh(sA[4], sA[5]);
                hf[d * 6 + 3] = pkh(cA[0], cA[1]);
                hf[d * 6 + 4] = pkh(cA[2], cA[3]);
                hf[d * 6 + 5] = pkh(cA[4], cA[5]);
            }
#pragma unroll
            for (int which = 0; which < 2; ++which) {
                const float* dv = (which == 0) ? wv : nv;
                const int ho = 18 + which * 4;
                const float nr = __builtin_amdgcn_sqrtf(dv[0]*dv[0] + dv[1]*dv[1] + dv[2]*dv[2]) + 1e-8f;
                const float u  = fast_atan2_rev(dv[1], dv[0]) + 0.5f;
                float zc = dv[2] * __builtin_amdgcn_rcpf(nr);
                zc = fminf(fmaxf(zc, -1.0f + 1e-6f), 1.0f - 1e-6f);
                const float vv = fast_acos(zc) * 0.3183098861837907f;
                float ob[8];
                blob4(u,  &ob[0]);
                blob4(vv, &ob[4]);
                hf[ho + 0] = pkh(ob[0], ob[1]);
                hf[ho + 1] = pkh(ob[2], ob[3]);
                hf[ho + 2] = pkh(ob[4], ob[5]);
                hf[ho + 3] = pkh(ob[6], ob[7]);
            }
            {
                float ob[4];
                blob4(1.0f - __expf(-rv), ob);
                hf[26] = pkh(ob[0], ob[1]);
                hf[27] = pkh(ob[2], ob[3]);
            }
            hf[28] = pkh(av[0], av[1]);
            hf[29] = pkh(av[2], bv[0]);
            hf[30] = pkh(bv[1], bv[2]);
            hf[31] = pkh(1.0f, 1.0f);
        } else {
            // ---------------- compute round r-1 (64 samples/wave) --------
            if (r > 0) {
                const int rr = r - 1;
                // read this round's B fragments (slice was staged last round)
                f16x8 bf[TILES][2];
#pragma unroll
                for (int t = 0; t < TILES; ++t) {
#pragma unroll
                    for (int kt = 0; kt < 2; ++kt) {
                        const int s0 = (16 * kt + 4 * q + 4 * m) & 31;
                        bf[t][kt] = *(const f16x8*)(
                            stg + t * 2048 + m * 128 + s0 * 4);
                    }
                }
                // alpha+beta prefetch (latency hidden under 6 layers)
                const int rbase = blk_base + rr * (PAIRS * 64) + pr * 64;
                float aa[TILES][3];
#pragma unroll
                for (int t = 0; t < TILES; ++t) {
                    const int s = rbase + t * 16 + m;
#pragma unroll
                    for (int d = 0; d < 3; ++d)
                        aa[t][d] = AL[s * 3 + d] + BE[s * 3 + d];
                }

                __builtin_amdgcn_s_setprio(1);
#pragma unroll
                for (int layer = 0; layer < 6; ++layer) {
                    f16x8 wa[8];   // frag index f = kt*4+mt
#pragma unroll
                    for (int f = 0; f < 8; ++f)
                        wa[f] = *(const f16x8*)(wb + (layer * 8 + f) * 1024);

#pragma unroll
                    for (int t = 0; t < TILES; ++t) {
                        f32x4 acc[4];
#pragma unroll
                        for (int mt = 0; mt < 4; ++mt) {
                            f32x4 z = MFMA32(wa[mt], bf[t][0], ZF);
                            z = MFMA32(wa[4 + mt], bf[t][1], z);
                            acc[mt] = z;
                        }
                        f16x4 pk[4];
#pragma unroll
                        for (int mt = 0; mt < 4; ++mt)
                            pk[mt] = __builtin_elementwise_max(pack4(acc[mt]), zero4);
                        bf[t][0] = cat44(pk[0], pk[1]);   // tau absorbed next
                        bf[t][1] = cat44(pk[2], pk[3]);
                    }
                }
                __builtin_amdgcn_s_setprio(0);
                // epilogue: W6 frags from LDS (wa dead here)
                const f16x8 w6f0 = *(const f16x8*)(wb + 48 * 1024);
                const f16x8 w6f1 = *(const f16x8*)(wb + 49 * 1024);
#pragma unroll
                for (int t = 0; t < TILES; ++t) {
                    f32x4 z = MFMA32(w6f0, bf[t][0], ZF);
                    z = MFMA32(w6f1, bf[t][1], z);
                    if (lane < 16) {   // q==0: D rows 0..2 = channels, col m
                        const int s = rbase + t * 16 + m;
                        float* o = Out + s * 3;
                        o[0] = z[0] * aa[t][0];
                        o[1] = z[1] * aa[t][1];
                        o[2] = z[2] * aa[t][2];
                    }
                }
            }
        }

        __syncthreads();   // barA: consumers finished reading slice(r-1)

        if (producer) {
            // stage all 4 tiles: sample (lane) -> tile lane>>4, row lane&15
            unsigned char* const tb = stg + (lane >> 4) * 2048 + m * 128;
#pragma unroll
            for (int g = 0; g < 8; ++g) {
                const int slot0 = (4 * g + 4 * m) & 31;
                *(f16x8*)(tb + slot0 * 4) =
                    cat44(cat22(hf[g*4 + 0], hf[g*4 + 1]),
                          cat22(hf[g*4 + 2], hf[g*4 + 3]));
            }
        }

        __syncthreads();   // barB: slice(r) staged; C computes it next window
    }

    // ---- drain: compute the final round ----
    if (!producer) {
        const int rr = ROUNDS - 1;
        f16x8 bf[TILES][2];
#pragma unroll
        for (int t = 0; t < TILES; ++t) {
#pragma unroll
            for (int kt = 0; kt < 2; ++kt) {
                const int s0 = (16 * kt + 4 * q + 4 * m) & 31;
                bf[t][kt] = *(const f16x8*)(stg + t * 2048 + m * 128 + s0 * 4);
            }
        }
        const int rbase = blk_base + rr * (PAIRS * 64) + pr * 64;
        float aa[TILES][3];
#pragma unroll
        for (int t = 0; t < TILES; ++t) {
            const int s = rbase + t * 16 + m;
#pragma unroll
            for (int d = 0; d < 3; ++d)
                aa[t][d] = AL[s * 3 + d] + BE[s * 3 + d];
        }
        __builtin_amdgcn_s_setprio(1);
#pragma unroll
        for (int layer = 0; layer < 6; ++layer) {
            f16x8 wa[8];
#pragma unroll
            for (int f = 0; f < 8; ++f)
                wa[f] = *(const f16x8*)(wb + (layer * 8 + f) * 1024);
#pragma unroll
            for (int t = 0; t < TILES; ++t) {
                f32x4 acc[4];
#pragma unroll
                for (int mt = 0; mt < 4; ++mt) {
                    f32x4 z = MFMA32(wa[mt], bf[t][0], ZF);
                    z = MFMA32(wa[4 + mt], bf[t][1], z);
                    acc[mt] = z;
                }
                f16x4 pk[4];
#pragma unroll
                for (int mt = 0; mt < 4; ++mt)
                    pk[mt] = __builtin_elementwise_max(pack4(acc[mt]), zero4);
                bf[t][0] = cat44(pk[0], pk[1]);
                bf[t][1] = cat44(pk[2], pk[3]);
            }
        }
        __builtin_amdgcn_s_setprio(0);
        const f16x8 w6f0 = *(const f16x8*)(wb + 48 * 1024);
        const f16x8 w6f1 = *(const f16x8*)(wb + 49 * 1024);
#pragma unroll
        for (int t = 0; t < TILES; ++t) {
            f32x4 z = MFMA32(w6f0, bf[t][0], ZF);
            z = MFMA32(w6f1, bf[t][1], z);
            if (lane < 16) {
                const int s = rbase + t * 16 + m;
                float* o = Out + s * 3;
                o[0] = z[0] * aa[t][0];
                o[1] = z[1] * aa[t][1];
                o[2] = z[2] * aa[t][2];
            }
        }
    }
}

extern "C" void kernel_launch(void* const* d_in, const int* in_sizes, int n_in,
                              void* d_out, int out_size, void* d_ws, size_t ws_size,
                              hipStream_t stream) {
    (void)n_in; (void)out_size;
    const float* P  = (const float*)d_in[0];
    const float* WI = (const float*)d_in[1];
    const float* NV = (const float*)d_in[2];
    const float* AL = (const float*)d_in[3];
    const float* BE = (const float*)d_in[4];
    const float* RR = (const float*)d_in[5];
    const float* W0 = (const float*)d_in[6];
    const float* W1 = (const float*)d_in[7];
    const float* W2 = (const float*)d_in[8];
    const float* W3 = (const float*)d_in[9];
    const float* W4 = (const float*)d_in[10];
    const float* W5 = (const float*)d_in[11];
    const float* W6 = (const float*)d_in[12];
    f16*   ws  = (f16*)d_ws;
    float* Out = (float*)d_out;

    const int Bn = in_sizes[0] / 3;     // 1,048,576
    const int grid = Bn / SPB;          // 512 blocks of 256 threads

    // ws_size fixed per session -> same path every call (graph-safe).
    if (ws_size >= WS_BYTES) {
        hipLaunchKernelGGL(pack_weights_kernel, dim3((WCHUNKS + 255) / 256),
                           dim3(256), 0, stream, W0, W1, W2, W3, W4, W5, W6, ws);
        hipLaunchKernelGGL((nrc_mlp_kernel<1>), dim3(grid), dim3(BLOCK), 0, stream,
                           P, WI, NV, AL, BE, RR, ws,
                           W0, W1, W2, W3, W4, W5, W6, Out);
    } else {
        hipLaunchKernelGGL((nrc_mlp_kernel<0>), dim3(grid), dim3(BLOCK), 0, stream,
                           P, WI, NV, AL, BE, RR, ws,
                           W0, W1, W2, W3, W4, W5, W6, Out);
    }
}

// Round 7
// 173.845 us; speedup vs baseline: 1.1167x; 1.0188x over previous
//
#include <hip/hip_runtime.h>

// NRC fused encode + 7-layer W=64 MLP. R20 = producer/consumer at FULL
// occupancy with the register-union problem eliminated at the source.
//
// Evidence base:
//  - Serialized-pipe model CONFIRMED: per 64-sample batch MFMA=3880cy
//    (19.4 cyc/mfma/SIMD from the 2PF 16x16 ceiling), VALU=4300cy;
//    (3880+4300)*16 batches/SIMD = 54.5us = R15's measured 56us.
//  - (512,4) allocator splits 128 regs ~64 VGPR/64 AGPR (R14:40@85cap,
//    R15/17/18: 64). hf(32)+bf(32) union at ANY shared point > 64 -> scratch
//    spill (R16-R18). R19 (2 waves/SIMD) starved both pipes: 92us.
//
// R20 design:
//  - 8 waves: w0-3 producers, w4-7 consumers -> every SIMD gets {P,C} from
//    each of 2 resident blocks = 2P+2C mixed phases, both pipes fed.
//  - hf[] ELIMINATED: encode streams each feature f16x4 straight to the
//    pair's LDS slice (16 ds_write_b64, rotated slots, 2-way conflicts=free).
//    Shared-point liveness: bf(32)+temps ~ 60 <= 64 arch.
//  - Round: {P: encode+stream(r) || C: compute(r-1)} -> bar1 ->
//           {C: read bf(r)} -> bar2 -> backedge. 2 barriers/round.
//  - LDS 75776 = W1-5+W6 image (43008) + 4 pair slices (32768); W0 frags
//    are re-read per round from the packed workspace (L2-hot, 8x b128).
//  - compute kt-outer: wa[4] (16 arch regs) per phase, acc[4][4] in AGPRs
//    (64), 16 independent MFMAs per phase. bf dummy-killed on P path.
//  - ROUNDS=8, SPB=2048, grid=512 -> exactly 2 blocks/CU, zero tail.
//
// 16x16x32 f16 fragment maps (verified):
//   A[m=lane&15][k=(lane>>4)*8+j], B[k=(lane>>4)*8+j][n=lane&15],
//   D[row=(lane>>4)*4+r][col=lane&15]  (4 blocks mt: row=mt*16+q*4+r)
// Chaining: bf[kt]=concat(relu(pack(acc[2kt])), relu(pack(acc[2kt+1])));
// k-index mismatch absorbed by permuting W1..W5,W6 columns with
// tau(x)=32(x>>5)+16((x&7)>>2)+4((x>>3)&3)+(x&3) at pack time.
// Staging slice layout (per pair, 8KB): sample row n at +n*128, dword D at
// slot (D+4n)&31 (write side = stream, read side = (16kt+4q+4m)&31, n=16t+m).

typedef _Float16 f16;
typedef f16 f16x2 __attribute__((ext_vector_type(2)));
typedef f16 f16x4 __attribute__((ext_vector_type(4)));
typedef f16 f16x8 __attribute__((ext_vector_type(8)));
typedef float f32x4 __attribute__((ext_vector_type(4)));

#define MFMA32(A, B, C) __builtin_amdgcn_mfma_f32_16x16x32_f16(A, B, C, 0, 0, 0)

static constexpr int TILES  = 4;        // 16-sample tiles per pair per round
static constexpr int WAVES  = 8;        // 4 producers + 4 consumers
static constexpr int BLOCK  = WAVES * 64;    // 512
static constexpr int PAIRS  = 4;
static constexpr int ROUNDS = 8;
static constexpr int SPB    = ROUNDS * PAIRS * 64;   // 2048

static constexpr int    WUNITS   = 50;      // 48 hidden frag-units + 2 W6
static constexpr int    WCHUNKS  = WUNITS * 64;           // 3200 x 16B
static constexpr size_t WS_BYTES = (size_t)WCHUNKS * 16;  // 51200
static constexpr int    LDSUNITS = 42;      // W1..W5 (40) + W6 (2) in LDS
static constexpr int    LDSCHNK  = LDSUNITS * 64;         // 2688
static constexpr int    LDS_WEI  = LDSUNITS * 1024;       // 43008
static constexpr int    LDS_STG  = PAIRS * 8192;          // 32768
static constexpr int    LDS_TOT  = LDS_WEI + LDS_STG;     // 75776

__host__ __device__ __forceinline__ int tau(int x) {
    return (x & 32) + ((x & 7) >> 2) * 16 + ((x >> 3) & 3) * 4 + (x & 3);
}

__device__ __forceinline__ f16x2 pkh(float a, float b) {
    return __builtin_bit_cast(f16x2, __builtin_amdgcn_cvt_pkrtz(a, b));
}

__device__ __forceinline__ f16x4 cat22(f16x2 a, f16x2 b) {
    return __builtin_shufflevector(a, b, 0, 1, 2, 3);
}

__device__ __forceinline__ f16x8 cat44(f16x4 a, f16x4 b) {
    return __builtin_shufflevector(a, b, 0, 1, 2, 3, 4, 5, 6, 7);
}

__device__ __forceinline__ f16x4 pack4(f32x4 v) {
    return cat22(pkh(v[0], v[1]), pkh(v[2], v[3]));
}

// atan2(y,x) / (2*pi)
__device__ __forceinline__ float fast_atan2_rev(float y, float x) {
    const float ax = __builtin_fabsf(x), ay = __builtin_fabsf(y);
    const float mx = fmaxf(ax, ay), mn = fminf(ax, ay);
    const float a = mn * __builtin_amdgcn_rcpf(fmaxf(mx, 1e-30f));
    const float s = a * a;
    float r = a * (0.99997726f + s * (-0.33262347f + s * (0.19354346f +
              s * (-0.11643287f + s * (0.05265332f - s * 0.01172120f)))));
    if (ay > ax) r = 1.5707963268f - r;
    if (x < 0.0f) r = 3.1415926536f - r;
    r = (y < 0.0f) ? -r : r;
    return r * 0.15915494309189535f;
}

// acos(x), |err| <= 6.8e-5 rad
__device__ __forceinline__ float fast_acos(float x) {
    const float ax = __builtin_fabsf(x);
    const float t = __builtin_amdgcn_sqrtf(1.0f - ax);
    const float p = t * (1.5707288f + ax * (-0.2121144f +
                    ax * (0.0742610f - ax * 0.0187293f)));
    return (x < 0.0f) ? (3.1415926536f - p) : p;
}

// one-blob: out[i]=exp(-8(x-c_i)^2) via exp ladder (2 transcendentals)
__device__ __forceinline__ void blob4(float x, float* out) {
    const float dx = x - 0.125f;
    const float E0 = __expf(-8.0f * dx * dx);
    const float R  = __expf(4.0f * dx);
    const float t1 = R * 0.60653066f;
    const float t2 = R * 0.22313016f;
    const float t3 = R * 0.082084999f;
    out[0] = E0;
    out[1] = E0 * t1;
    out[2] = out[1] * t2;
    out[3] = out[2] * t3;
}

// compute packed-weight chunk c (= unit*64 + lane2) from the f32 weights
__device__ __forceinline__ f16x8 make_wchunk(
    int c, const float* __restrict__ W0, const float* __restrict__ W1,
    const float* __restrict__ W2, const float* __restrict__ W3,
    const float* __restrict__ W4, const float* __restrict__ W5,
    const float* __restrict__ W6)
{
    const int lane2 = c & 63;
    const int unit  = c >> 6;
    const int q = lane2 >> 4, m = lane2 & 15;
    f16x8 v;
    if (unit < 48) {
        const int l = unit >> 3, kt = (unit & 7) >> 2, mt = unit & 3;
        const float* Ws[6] = {W0, W1, W2, W3, W4, W5};
        const float* __restrict__ Wl = Ws[l];
#pragma unroll
        for (int j = 0; j < 8; ++j) {
            const int x = kt * 32 + q * 8 + j;
            const int src = (l == 0) ? x : tau(x);
            v[j] = (f16)Wl[(mt * 16 + m) * 64 + src];
        }
    } else {
        const int kt = unit - 48;
#pragma unroll
        for (int j = 0; j < 8; ++j) {
            const int src = tau(kt * 32 + q * 8 + j);
            v[j] = (m < 3) ? (f16)W6[m * 64 + src] : (f16)0.0f;
        }
    }
    return v;
}

__global__ __launch_bounds__(256, 1) void pack_weights_kernel(
    const float* __restrict__ W0, const float* __restrict__ W1,
    const float* __restrict__ W2, const float* __restrict__ W3,
    const float* __restrict__ W4, const float* __restrict__ W5,
    const float* __restrict__ W6, f16* __restrict__ ws)
{
    const int c = (int)blockIdx.x * 256 + threadIdx.x;
    if (c >= WCHUNKS) return;
    *(f16x8*)(ws + (size_t)c * 8) = make_wchunk(c, W0, W1, W2, W3, W4, W5, W6);
}

// async global->LDS DMA, 16B per lane (wave-uniform LDS base + lane*16).
__device__ __forceinline__ void async_ld16(const void* g, void* l) {
    __builtin_amdgcn_global_load_lds(
        (const __attribute__((address_space(1))) void*)g,
        (__attribute__((address_space(3))) void*)l,
        16, 0, 0);
}

template<int PACKED>
__global__ __launch_bounds__(BLOCK, 4) void nrc_mlp_kernel(
    const float* __restrict__ P,  const float* __restrict__ WI,
    const float* __restrict__ NV, const float* __restrict__ AL,
    const float* __restrict__ BE, const float* __restrict__ RR,
    const f16*   __restrict__ ws,
    const float* __restrict__ W0, const float* __restrict__ W1,
    const float* __restrict__ W2, const float* __restrict__ W3,
    const float* __restrict__ W4, const float* __restrict__ W5,
    const float* __restrict__ W6, float* __restrict__ Out)
{
    // [0,43008): W1..W5 + W6 frag image (unit u at (u-8)*1024 + lane*16).
    // [43008,75776): 4 pair slices x 8KB (64 sample-rows x 128B, rotated).
    __shared__ __attribute__((aligned(16))) unsigned char smem[LDS_TOT];

    const int tid  = threadIdx.x;
    const int lane = tid & 63;
    const int w    = tid >> 6;
    const int q    = lane >> 4;
    const int m    = lane & 15;
    const bool prod = (w < PAIRS);
    const int  p    = prod ? w : (w - PAIRS);
    const int  blk_base = (int)blockIdx.x * SPB;

    unsigned char* const stgp = smem + LDS_WEI + p * 8192;
    unsigned char* const wbl  = smem + lane * 16;   // weight-image lane base

    // ---- weight image W1..W6 -> LDS (W0 stays in ws / recomputed) ----
    if (PACKED) {
#pragma unroll
        for (int i = 0; i < 6; ++i) {
            const int c = i * BLOCK + tid;
            if (c < LDSCHNK)
                async_ld16(ws + (size_t)(512 + c) * 8, smem + c * 16);
        }
    } else {
#pragma unroll
        for (int i = 0; i < 6; ++i) {
            const int c = i * BLOCK + tid;
            if (c < LDSCHNK)
                *(f16x8*)(smem + c * 16) =
                    make_wchunk(512 + c, W0, W1, W2, W3, W4, W5, W6);
        }
    }

    const f16x4 zero4 = {(f16)0.0f, (f16)0.0f, (f16)0.0f, (f16)0.0f};
    const f32x4 ZF = {0.0f, 0.0f, 0.0f, 0.0f};

    f16x8 bf[TILES][2];   // consumer: one round's B fragments

    // ---- consumer: full MLP + store for round rr (kt-outer, acc in AGPRs) --
    auto compute = [&](int rr) {
        __builtin_amdgcn_s_setprio(1);
        f32x4 acc[TILES][4];
#pragma unroll
        for (int layer = 0; layer < 6; ++layer) {
            f16x8 wa[4];
            // kt = 0 fragments (f = mt)
            if (layer == 0) {
                if (PACKED) {
#pragma unroll
                    for (int mt = 0; mt < 4; ++mt)
                        wa[mt] = *(const f16x8*)(ws + (size_t)(mt * 64 + lane) * 8);
                } else {
#pragma unroll
                    for (int mt = 0; mt < 4; ++mt)
                        wa[mt] = make_wchunk(mt * 64 + lane, W0, W1, W2, W3, W4, W5, W6);
                }
            } else {
#pragma unroll
                for (int mt = 0; mt < 4; ++mt)
                    wa[mt] = *(const f16x8*)(wbl + ((layer - 1) * 8 + mt) * 1024);
            }
#pragma unroll
            for (int t = 0; t < TILES; ++t)
#pragma unroll
                for (int mt = 0; mt < 4; ++mt)
                    acc[t][mt] = MFMA32(wa[mt], bf[t][0], ZF);
            // kt = 1 fragments (f = 4 + mt)
            if (layer == 0) {
                if (PACKED) {
#pragma unroll
                    for (int mt = 0; mt < 4; ++mt)
                        wa[mt] = *(const f16x8*)(ws + (size_t)((4 + mt) * 64 + lane) * 8);
                } else {
#pragma unroll
                    for (int mt = 0; mt < 4; ++mt)
                        wa[mt] = make_wchunk((4 + mt) * 64 + lane, W0, W1, W2, W3, W4, W5, W6);
                }
            } else {
#pragma unroll
                for (int mt = 0; mt < 4; ++mt)
                    wa[mt] = *(const f16x8*)(wbl + ((layer - 1) * 8 + 4 + mt) * 1024);
            }
#pragma unroll
            for (int t = 0; t < TILES; ++t)
#pragma unroll
                for (int mt = 0; mt < 4; ++mt)
                    acc[t][mt] = MFMA32(wa[mt], bf[t][1], acc[t][mt]);
            // relu + repack (tau absorbed in next layer's packed columns)
#pragma unroll
            for (int t = 0; t < TILES; ++t) {
                f16x4 pk[4];
#pragma unroll
                for (int mt = 0; mt < 4; ++mt)
                    pk[mt] = __builtin_elementwise_max(pack4(acc[t][mt]), zero4);
                bf[t][0] = cat44(pk[0], pk[1]);
                bf[t][1] = cat44(pk[2], pk[3]);
            }
        }
        __builtin_amdgcn_s_setprio(0);
        // ---- W6 (LDS units 40,41) + alpha/beta scale + store ----
        const int rbase = blk_base + rr * (PAIRS * 64) + p * 64;
        float aa[TILES][3];
#pragma unroll
        for (int t = 0; t < TILES; ++t) {
            const int s = rbase + t * 16 + m;
#pragma unroll
            for (int d = 0; d < 3; ++d)
                aa[t][d] = AL[s * 3 + d] + BE[s * 3 + d];
        }
        f32x4 oz[TILES];
        {
            const f16x8 w6a = *(const f16x8*)(wbl + 40 * 1024);
#pragma unroll
            for (int t = 0; t < TILES; ++t) oz[t] = MFMA32(w6a, bf[t][0], ZF);
            const f16x8 w6b = *(const f16x8*)(wbl + 41 * 1024);
#pragma unroll
            for (int t = 0; t < TILES; ++t) oz[t] = MFMA32(w6b, bf[t][1], oz[t]);
        }
#pragma unroll
        for (int t = 0; t < TILES; ++t) {
            if (lane < 16) {   // q==0: D rows 0..2 = output channels, col m
                const int s = rbase + t * 16 + m;
                float* o = Out + s * 3;
                o[0] = oz[t][0] * aa[t][0];
                o[1] = oz[t][1] * aa[t][1];
                o[2] = oz[t][2] * aa[t][2];
            }
        }
    };

    // ---- rounds: {P: encode-stream(r) || C: compute(r-1)} bar {C: read} bar
    for (int r = 0; r < ROUNDS; ++r) {
        if (prod) {
            // kill bf's static live range through the encode body (P never
            // redefines it otherwise; path-insensitive liveness would union
            // bf with encode temps -- the R17/R18 spill mechanism).
#pragma unroll
            for (int t = 0; t < TILES; ++t) {
                bf[t][0] = f16x8{};
                bf[t][1] = f16x8{};
            }
            const int s = blk_base + r * (PAIRS * 64) + p * 64 + lane;
            unsigned char* const myrow = stgp + lane * 128;
            const int rot = (lane * 4) & 31;
            auto put = [&](int D, f16x2 a, f16x2 b) {
                *(f16x4*)(myrow + (((D + rot) & 31) << 2)) = cat22(a, b);
            };

            const float3 pv = *(const float3*)(P  + 3 * s);
            const float3 wv = *(const float3*)(WI + 3 * s);
            const float3 nv = *(const float3*)(NV + 3 * s);
            const float3 av = *(const float3*)(AL + 3 * s);
            const float3 bv = *(const float3*)(BE + 3 * s);
            const float  rv = RR[s];
            const float parr[3] = {pv.x, pv.y, pv.z};

            // freq embed: base sin/cos at pi*p (revolutions) + angle doubling
#pragma unroll
            for (int d = 0; d < 3; ++d) {
                float sA[6], cA[6];
                const float fr = __builtin_amdgcn_fractf(parr[d] * 0.5f);
                sA[0] = __builtin_amdgcn_sinf(fr);
                cA[0] = __builtin_amdgcn_cosf(fr);
#pragma unroll
                for (int k = 1; k < 6; ++k) {
                    const float s2 = sA[k-1] * sA[k-1];
                    const float sc = sA[k-1] * cA[k-1];
                    cA[k] = fmaf(-2.0f, s2, 1.0f);
                    sA[k] = sc + sc;
                }
                put(6 * d + 0, pkh(sA[0], sA[1]), pkh(sA[2], sA[3]));
                put(6 * d + 2, pkh(sA[4], sA[5]), pkh(cA[0], cA[1]));
                put(6 * d + 4, pkh(cA[2], cA[3]), pkh(cA[4], cA[5]));
            }
#pragma unroll
            for (int which = 0; which < 2; ++which) {
                const float3 dv3 = (which == 0) ? wv : nv;
                const float dx = dv3.x, dy = dv3.y, dz = dv3.z;
                const int D0 = 18 + which * 4;
                const float nr = __builtin_amdgcn_sqrtf(dx*dx + dy*dy + dz*dz) + 1e-8f;
                const float u  = fast_atan2_rev(dy, dx) + 0.5f;
                float zc = dz * __builtin_amdgcn_rcpf(nr);
                zc = fminf(fmaxf(zc, -1.0f + 1e-6f), 1.0f - 1e-6f);
                const float vv = fast_acos(zc) * 0.3183098861837907f;
                float ob[8];
                blob4(u,  &ob[0]);
                blob4(vv, &ob[4]);
                put(D0,     pkh(ob[0], ob[1]), pkh(ob[2], ob[3]));
                put(D0 + 2, pkh(ob[4], ob[5]), pkh(ob[6], ob[7]));
            }
            {
                float ob[4];
                blob4(1.0f - __expf(-rv), ob);
                put(26, pkh(ob[0], ob[1]), pkh(ob[2], ob[3]));
            }
            put(28, pkh(av.x, av.y), pkh(av.z, bv.x));
            put(30, pkh(bv.y, bv.z), pkh(1.0f, 1.0f));
        } else if (r > 0) {
            compute(r - 1);       // overlaps producers' encode of round r
        }

        __syncthreads();   // bar1: slice(r) fully written; weights DMA'd (r=0)

        if (!prod) {
#pragma unroll
            for (int t = 0; t < TILES; ++t) {
                const int n = t * 16 + m;
#pragma unroll
                for (int kt = 0; kt < 2; ++kt) {
                    const int s0 = (16 * kt + 4 * q + 4 * m) & 31;
                    bf[t][kt] = *(const f16x8*)(stgp + n * 128 + (s0 << 2));
                }
            }
        }

        __syncthreads();   // bar2: reads done; P may overwrite slice next round
    }
    if (!prod) compute(ROUNDS - 1);   // drain
}

extern "C" void kernel_launch(void* const* d_in, const int* in_sizes, int n_in,
                              void* d_out, int out_size, void* d_ws, size_t ws_size,
                              hipStream_t stream) {
    (void)n_in; (void)out_size;
    const float* P  = (const float*)d_in[0];
    const float* WI = (const float*)d_in[1];
    const float* NV = (const float*)d_in[2];
    const float* AL = (const float*)d_in[3];
    const float* BE = (const float*)d_in[4];
    const float* RR = (const float*)d_in[5];
    const float* W0 = (const float*)d_in[6];
    const float* W1 = (const float*)d_in[7];
    const float* W2 = (const float*)d_in[8];
    const float* W3 = (const float*)d_in[9];
    const float* W4 = (const float*)d_in[10];
    const float* W5 = (const float*)d_in[11];
    const float* W6 = (const float*)d_in[12];
    f16*   ws  = (f16*)d_ws;
    float* Out = (float*)d_out;

    const int Bn = in_sizes[0] / 3;     // 1,048,576
    const int grid = Bn / SPB;          // 512 blocks of 512 threads

    // ws_size fixed per session -> same path every call (graph-safe).
    if (ws_size >= WS_BYTES) {
        hipLaunchKernelGGL(pack_weights_kernel, dim3((WCHUNKS + 255) / 256),
                           dim3(256), 0, stream, W0, W1, W2, W3, W4, W5, W6, ws);
        hipLaunchKernelGGL((nrc_mlp_kernel<1>), dim3(grid), dim3(BLOCK), 0, stream,
                           P, WI, NV, AL, BE, RR, ws,
                           W0, W1, W2, W3, W4, W5, W6, Out);
    } else {
        hipLaunchKernelGGL((nrc_mlp_kernel<0>), dim3(grid), dim3(BLOCK), 0, stream,
                           P, WI, NV, AL, BE, RR, ws,
                           W0, W1, W2, W3, W4, W5, W6, Out);
    }
}

// Round 8
// 160.307 us; speedup vs baseline: 1.2110x; 1.0845x over previous
//
#include <hip/hip_runtime.h>

// NRC fused encode + 7-layer W=64 MLP. R21 = intra-wave software pipeline in
// the big-register regime (no wave roles, no in-loop barriers).
//
// History: R15 lockstep = 56us (MfmaUtil 40 + VALUBusy 51 summed -> pipes
// serialize; model: 3880cy MFMA + 4300cy VALU per 64-sample batch x16/SIMD
// = 54.5us, matches). R16-R20 producer/consumer: all lost to R15 -- fused
// P+C bodies spill at the 128-reg envelope (R16/17/18/20), role-split at
// 2 waves/SIMD starves both pipes (R19, 92us).
//
// R21: each wave is its own producer AND consumer. While running batch i's
// 6-layer MFMA chain it interleaves batch i+1's encode as 6 VALU slices
// (one per layer), streamed to a wave-PRIVATE 8KB LDS slice (R20's verified
// put/read layout). In-order issue alternates MFMA/VALU blocks; 2 waves/SIMD
// drift out of phase and cover each other -> both pipes fed, no barriers in
// the whole main loop (single __syncthreads for the weight image).
//  - BLOCK=256 (4 waves), __launch_bounds__(256,2) -> 256 regs/wave:
//    spills structurally impossible (~160 peak incl. W0 in registers).
//  - LDS 75776 = W1..W6 image (42 units, R20 arrangement) + 4 x 8KB slices;
//    2 blocks/CU = 8 waves/CU = 2 waves/SIMD.
//  - W0 -> 8 persistent register frags (loaded once from packed ws).
//  - NB=8 batches x 64 samples per wave, SPB=2048, grid=512 exact.
//  - inputs prefetched 2 batches ahead (cur/nxt); alpha+beta kept in regs,
//    delivered to the epilogue via __shfl (R15-verified pattern).
//
// 16x16x32 f16 fragment maps (verified):
//   A[m=lane&15][k=(lane>>4)*8+j], B[k=(lane>>4)*8+j][n=lane&15],
//   D[row=(lane>>4)*4+r][col=lane&15]  (4 blocks mt: row=mt*16+q*4+r)
// Chaining: bf[kt]=concat(relu(pack(acc[2kt])), relu(pack(acc[2kt+1])));
// k-index mismatch absorbed by permuting W1..W5,W6 columns with
// tau(x)=32(x>>5)+16((x&7)>>2)+4((x>>3)&3)+(x&3) at pack time.
// Staging slice (per wave, 8KB): sample row n at +n*128, dword D at slot
// (D+4n)&31; write rot=(4*lane)&31, read s0=(16kt+4q+4m)&31 (R20-verified).

typedef _Float16 f16;
typedef f16 f16x2 __attribute__((ext_vector_type(2)));
typedef f16 f16x4 __attribute__((ext_vector_type(4)));
typedef f16 f16x8 __attribute__((ext_vector_type(8)));
typedef float f32x4 __attribute__((ext_vector_type(4)));

#define MFMA32(A, B, C) __builtin_amdgcn_mfma_f32_16x16x32_f16(A, B, C, 0, 0, 0)
#define LDS_FENCE() __asm__ volatile("" ::: "memory")

static constexpr int TILES  = 4;        // 16-sample tiles per batch
static constexpr int WAVES  = 4;
static constexpr int BLOCK  = WAVES * 64;    // 256
static constexpr int NB     = 8;        // batches per wave
static constexpr int SPB    = WAVES * NB * 64;   // 2048

static constexpr int    WUNITS   = 50;      // packed image: 48 hidden + 2 W6
static constexpr int    WCHUNKS  = WUNITS * 64;           // 3200 x 16B
static constexpr size_t WS_BYTES = (size_t)WCHUNKS * 16;  // 51200
static constexpr int    LDSUNITS = 42;      // W1..W5 (40) + W6 (2) in LDS
static constexpr int    LDSCHNK  = LDSUNITS * 64;         // 2688
static constexpr int    LDS_WEI  = LDSUNITS * 1024;       // 43008
static constexpr int    LDS_STG  = WAVES * 8192;          // 32768
static constexpr int    LDS_TOT  = LDS_WEI + LDS_STG;     // 75776

__host__ __device__ __forceinline__ int tau(int x) {
    return (x & 32) + ((x & 7) >> 2) * 16 + ((x >> 3) & 3) * 4 + (x & 3);
}

__device__ __forceinline__ f16x2 pkh(float a, float b) {
    return __builtin_bit_cast(f16x2, __builtin_amdgcn_cvt_pkrtz(a, b));
}

__device__ __forceinline__ f16x4 cat22(f16x2 a, f16x2 b) {
    return __builtin_shufflevector(a, b, 0, 1, 2, 3);
}

__device__ __forceinline__ f16x8 cat44(f16x4 a, f16x4 b) {
    return __builtin_shufflevector(a, b, 0, 1, 2, 3, 4, 5, 6, 7);
}

__device__ __forceinline__ f16x4 pack4(f32x4 v) {
    return cat22(pkh(v[0], v[1]), pkh(v[2], v[3]));
}

// atan2(y,x) / (2*pi)
__device__ __forceinline__ float fast_atan2_rev(float y, float x) {
    const float ax = __builtin_fabsf(x), ay = __builtin_fabsf(y);
    const float mx = fmaxf(ax, ay), mn = fminf(ax, ay);
    const float a = mn * __builtin_amdgcn_rcpf(fmaxf(mx, 1e-30f));
    const float s = a * a;
    float r = a * (0.99997726f + s * (-0.33262347f + s * (0.19354346f +
              s * (-0.11643287f + s * (0.05265332f - s * 0.01172120f)))));
    if (ay > ax) r = 1.5707963268f - r;
    if (x < 0.0f) r = 3.1415926536f - r;
    r = (y < 0.0f) ? -r : r;
    return r * 0.15915494309189535f;
}

// acos(x), |err| <= 6.8e-5 rad
__device__ __forceinline__ float fast_acos(float x) {
    const float ax = __builtin_fabsf(x);
    const float t = __builtin_amdgcn_sqrtf(1.0f - ax);
    const float p = t * (1.5707288f + ax * (-0.2121144f +
                    ax * (0.0742610f - ax * 0.0187293f)));
    return (x < 0.0f) ? (3.1415926536f - p) : p;
}

// one-blob: out[i]=exp(-8(x-c_i)^2) via exp ladder (2 transcendentals)
__device__ __forceinline__ void blob4(float x, float* out) {
    const float dx = x - 0.125f;
    const float E0 = __expf(-8.0f * dx * dx);
    const float R  = __expf(4.0f * dx);
    const float t1 = R * 0.60653066f;
    const float t2 = R * 0.22313016f;
    const float t3 = R * 0.082084999f;
    out[0] = E0;
    out[1] = E0 * t1;
    out[2] = out[1] * t2;
    out[3] = out[2] * t3;
}

// compute packed-weight chunk c (= unit*64 + lane2) from the f32 weights
__device__ __forceinline__ f16x8 make_wchunk(
    int c, const float* __restrict__ W0, const float* __restrict__ W1,
    const float* __restrict__ W2, const float* __restrict__ W3,
    const float* __restrict__ W4, const float* __restrict__ W5,
    const float* __restrict__ W6)
{
    const int lane2 = c & 63;
    const int unit  = c >> 6;
    const int q = lane2 >> 4, m = lane2 & 15;
    f16x8 v;
    if (unit < 48) {
        const int l = unit >> 3, kt = (unit & 7) >> 2, mt = unit & 3;
        const float* Ws[6] = {W0, W1, W2, W3, W4, W5};
        const float* __restrict__ Wl = Ws[l];
#pragma unroll
        for (int j = 0; j < 8; ++j) {
            const int x = kt * 32 + q * 8 + j;
            const int src = (l == 0) ? x : tau(x);
            v[j] = (f16)Wl[(mt * 16 + m) * 64 + src];
        }
    } else {
        const int kt = unit - 48;
#pragma unroll
        for (int j = 0; j < 8; ++j) {
            const int src = tau(kt * 32 + q * 8 + j);
            v[j] = (m < 3) ? (f16)W6[m * 64 + src] : (f16)0.0f;
        }
    }
    return v;
}

__global__ __launch_bounds__(256, 1) void pack_weights_kernel(
    const float* __restrict__ W0, const float* __restrict__ W1,
    const float* __restrict__ W2, const float* __restrict__ W3,
    const float* __restrict__ W4, const float* __restrict__ W5,
    const float* __restrict__ W6, f16* __restrict__ ws)
{
    const int c = (int)blockIdx.x * 256 + threadIdx.x;
    if (c >= WCHUNKS) return;
    *(f16x8*)(ws + (size_t)c * 8) = make_wchunk(c, W0, W1, W2, W3, W4, W5, W6);
}

// async global->LDS DMA, 16B per lane (wave-uniform LDS base + lane*16).
__device__ __forceinline__ void async_ld16(const void* g, void* l) {
    __builtin_amdgcn_global_load_lds(
        (const __attribute__((address_space(1))) void*)g,
        (__attribute__((address_space(3))) void*)l,
        16, 0, 0);
}

struct EncIn {
    float pv[3], wv[3], nv[3], av[3], bv[3], rv;
};

__device__ __forceinline__ EncIn load_inputs(
    const float* __restrict__ P,  const float* __restrict__ WI,
    const float* __restrict__ NV, const float* __restrict__ AL,
    const float* __restrict__ BE, const float* __restrict__ RR, int s)
{
    EncIn e;
#pragma unroll
    for (int d = 0; d < 3; ++d) {
        e.pv[d] = P [s * 3 + d];
        e.wv[d] = WI[s * 3 + d];
        e.nv[d] = NV[s * 3 + d];
        e.av[d] = AL[s * 3 + d];
        e.bv[d] = BE[s * 3 + d];
    }
    e.rv = RR[s];
    return e;
}

// one encode slice (k = 0..5), writes its features to the wave-private slice.
// k is a compile-time constant at every call site (unrolled layer loop).
__device__ __forceinline__ void enc_slice(
    int k, const EncIn& e, unsigned char* myrow, int rot, float* abn)
{
    auto put = [&](int D, f16x2 a, f16x2 b) {
        *(f16x4*)(myrow + (((D + rot) & 31) << 2)) = cat22(a, b);
    };
    if (k <= 2) {
        const int d = k;   // freq embed dim d
        float sA[6], cA[6];
        const float fr = __builtin_amdgcn_fractf(e.pv[d] * 0.5f);
        sA[0] = __builtin_amdgcn_sinf(fr);
        cA[0] = __builtin_amdgcn_cosf(fr);
#pragma unroll
        for (int kk = 1; kk < 6; ++kk) {
            const float s2 = sA[kk-1] * sA[kk-1];
            const float sc = sA[kk-1] * cA[kk-1];
            cA[kk] = fmaf(-2.0f, s2, 1.0f);
            sA[kk] = sc + sc;
        }
        put(6*d + 0, pkh(sA[0], sA[1]), pkh(sA[2], sA[3]));
        put(6*d + 2, pkh(sA[4], sA[5]), pkh(cA[0], cA[1]));
        put(6*d + 4, pkh(cA[2], cA[3]), pkh(cA[4], cA[5]));
    } else if (k <= 4) {
        const int which = k - 3;   // 0: wi, 1: n
        const float dx = which ? e.nv[0] : e.wv[0];
        const float dy = which ? e.nv[1] : e.wv[1];
        const float dz = which ? e.nv[2] : e.wv[2];
        const int D0 = 18 + which * 4;
        const float nr = __builtin_amdgcn_sqrtf(dx*dx + dy*dy + dz*dz) + 1e-8f;
        const float u  = fast_atan2_rev(dy, dx) + 0.5f;
        float zc = dz * __builtin_amdgcn_rcpf(nr);
        zc = fminf(fmaxf(zc, -1.0f + 1e-6f), 1.0f - 1e-6f);
        const float vv = fast_acos(zc) * 0.3183098861837907f;
        float ob[8];
        blob4(u,  &ob[0]);
        blob4(vv, &ob[4]);
        put(D0,     pkh(ob[0], ob[1]), pkh(ob[2], ob[3]));
        put(D0 + 2, pkh(ob[4], ob[5]), pkh(ob[6], ob[7]));
    } else {
        float ob[4];
        blob4(1.0f - __expf(-e.rv), ob);
        put(26, pkh(ob[0], ob[1]), pkh(ob[2], ob[3]));
        put(28, pkh(e.av[0], e.av[1]), pkh(e.av[2], e.bv[0]));
        put(30, pkh(e.bv[1], e.bv[2]), pkh(1.0f, 1.0f));
        abn[0] = e.av[0] + e.bv[0];
        abn[1] = e.av[1] + e.bv[1];
        abn[2] = e.av[2] + e.bv[2];
    }
}

template<int PACKED>
__global__ __launch_bounds__(BLOCK, 2) void nrc_mlp_kernel(
    const float* __restrict__ P,  const float* __restrict__ WI,
    const float* __restrict__ NV, const float* __restrict__ AL,
    const float* __restrict__ BE, const float* __restrict__ RR,
    const f16*   __restrict__ ws,
    const float* __restrict__ W0, const float* __restrict__ W1,
    const float* __restrict__ W2, const float* __restrict__ W3,
    const float* __restrict__ W4, const float* __restrict__ W5,
    const float* __restrict__ W6, float* __restrict__ Out)
{
    // [0,43008): W1..W5 + W6 frag image (packed unit u at (u-8)*1024+lane*16).
    // [43008,75776): 4 wave-private 8KB slices (64 rows x 128B, rotated).
    __shared__ __attribute__((aligned(16))) unsigned char smem[LDS_TOT];

    const int tid  = threadIdx.x;
    const int lane = tid & 63;
    const int w    = tid >> 6;
    const int q    = lane >> 4;
    const int m    = lane & 15;
    const int wave_base = (int)blockIdx.x * SPB + w * (NB * 64);

    unsigned char* const stgw  = smem + LDS_WEI + w * 8192;
    unsigned char* const myrow = stgw + lane * 128;
    const int rot = (lane * 4) & 31;
    unsigned char* const wbl   = smem + lane * 16;

    // ---- weight image W1..W6 -> LDS (async DMA / VALU fallback) ----
    if (PACKED) {
#pragma unroll
        for (int i = 0; i < (LDSCHNK + BLOCK - 1) / BLOCK; ++i) {
            const int c = i * BLOCK + tid;
            if (c < LDSCHNK)
                async_ld16(ws + (size_t)(512 + c) * 8, smem + c * 16);
        }
    } else {
#pragma unroll
        for (int i = 0; i < (LDSCHNK + BLOCK - 1) / BLOCK; ++i) {
            const int c = i * BLOCK + tid;
            if (c < LDSCHNK)
                *(f16x8*)(smem + c * 16) =
                    make_wchunk(512 + c, W0, W1, W2, W3, W4, W5, W6);
        }
    }

    // ---- W0: 8 persistent register fragments (read once per wave) ----
    f16x8 w0f[8];
    if (PACKED) {
#pragma unroll
        for (int f = 0; f < 8; ++f)
            w0f[f] = *(const f16x8*)(ws + (size_t)(f * 64 + lane) * 8);
    } else {
#pragma unroll
        for (int f = 0; f < 8; ++f)
            w0f[f] = make_wchunk(f * 64 + lane, W0, W1, W2, W3, W4, W5, W6);
    }

    // ---- prologue: encode batch 0 into the wave-private slice ----
    float ab_cur[3], abn[3];
    {
        EncIn e0 = load_inputs(P, WI, NV, AL, BE, RR, wave_base + lane);
#pragma unroll
        for (int k = 0; k < 6; ++k)
            enc_slice(k, e0, myrow, rot, abn);
        ab_cur[0] = abn[0]; ab_cur[1] = abn[1]; ab_cur[2] = abn[2];
    }

    __syncthreads();   // weight image complete (the ONLY barrier)

    const f16x4 zero4 = {(f16)0.0f, (f16)0.0f, (f16)0.0f, (f16)0.0f};
    const f32x4 ZF = {0.0f, 0.0f, 0.0f, 0.0f};

    // ---- read batch 0's B fragments ----
    f16x8 bf[TILES][2];
    LDS_FENCE();
#pragma unroll
    for (int t = 0; t < TILES; ++t)
#pragma unroll
        for (int kt = 0; kt < 2; ++kt) {
            const int s0 = (16 * kt + 4 * q + 4 * m) & 31;
            bf[t][kt] = *(const f16x8*)(stgw + (t * 16 + m) * 128 + (s0 << 2));
        }
    LDS_FENCE();

    EncIn cur = load_inputs(P, WI, NV, AL, BE, RR, wave_base + 64 + lane);
    EncIn nxt = cur;

    // ---- batch loop: layers(b) interleaved with encode slices(b+1) ----
#pragma unroll 1
    for (int b = 0; b < NB; ++b) {
        const bool hn = (b + 1 < NB);
        if (b + 2 < NB)
            nxt = load_inputs(P, WI, NV, AL, BE, RR,
                              wave_base + (b + 2) * 64 + lane);

        f32x4 acc[TILES][4];
#pragma unroll
        for (int layer = 0; layer < 6; ++layer) {
            f16x8 wa[4];
            __builtin_amdgcn_s_setprio(1);
            // kt = 0 fragments
            if (layer == 0) {
#pragma unroll
                for (int mt = 0; mt < 4; ++mt) wa[mt] = w0f[mt];
            } else {
#pragma unroll
                for (int mt = 0; mt < 4; ++mt)
                    wa[mt] = *(const f16x8*)(wbl + ((layer - 1) * 8 + mt) * 1024);
            }
#pragma unroll
            for (int t = 0; t < TILES; ++t)
#pragma unroll
                for (int mt = 0; mt < 4; ++mt)
                    acc[t][mt] = MFMA32(wa[mt], bf[t][0], ZF);
            // kt = 1 fragments
            if (layer == 0) {
#pragma unroll
                for (int mt = 0; mt < 4; ++mt) wa[mt] = w0f[4 + mt];
            } else {
#pragma unroll
                for (int mt = 0; mt < 4; ++mt)
                    wa[mt] = *(const f16x8*)(wbl + ((layer - 1) * 8 + 4 + mt) * 1024);
            }
#pragma unroll
            for (int t = 0; t < TILES; ++t)
#pragma unroll
                for (int mt = 0; mt < 4; ++mt)
                    acc[t][mt] = MFMA32(wa[mt], bf[t][1], acc[t][mt]);
            __builtin_amdgcn_s_setprio(0);

            // encode slice of batch b+1 runs in the MFMA shadow (VALU pipe)
            if (hn) enc_slice(layer, cur, myrow, rot, abn);

            // relu + repack (waits on this layer's MFMAs)
#pragma unroll
            for (int t = 0; t < TILES; ++t) {
                f16x4 pk[4];
#pragma unroll
                for (int mt = 0; mt < 4; ++mt)
                    pk[mt] = __builtin_elementwise_max(pack4(acc[t][mt]), zero4);
                bf[t][0] = cat44(pk[0], pk[1]);   // tau absorbed next layer
                bf[t][1] = cat44(pk[2], pk[3]);
            }
        }

        // ---- epilogue: W6 (LDS units 40,41) + (alpha+beta) scale + store ----
        {
            const int rbase = wave_base + b * 64;
            f32x4 oz[TILES];
            const f16x8 w6a = *(const f16x8*)(wbl + 40 * 1024);
#pragma unroll
            for (int t = 0; t < TILES; ++t) oz[t] = MFMA32(w6a, bf[t][0], ZF);
            const f16x8 w6b = *(const f16x8*)(wbl + 41 * 1024);
#pragma unroll
            for (int t = 0; t < TILES; ++t) oz[t] = MFMA32(w6b, bf[t][1], oz[t]);
#pragma unroll
            for (int t = 0; t < TILES; ++t) {
                // ab of sample t*16+m lives in lane t*16+m's registers
                const float s0 = __shfl(ab_cur[0], t * 16 + m);
                const float s1 = __shfl(ab_cur[1], t * 16 + m);
                const float s2 = __shfl(ab_cur[2], t * 16 + m);
                if (lane < 16) {   // q==0: D rows 0..2 = out channels, col m
                    const int s = rbase + t * 16 + m;
                    float* o = Out + s * 3;
                    o[0] = oz[t][0] * s0;
                    o[1] = oz[t][1] * s1;
                    o[2] = oz[t][2] * s2;
                }
            }
        }

        // ---- batch switch: pull in batch b+1 (written during the layers) ----
        if (hn) {
            ab_cur[0] = abn[0]; ab_cur[1] = abn[1]; ab_cur[2] = abn[2];
            LDS_FENCE();   // slice writes ordered before reads (same wave)
#pragma unroll
            for (int t = 0; t < TILES; ++t)
#pragma unroll
                for (int kt = 0; kt < 2; ++kt) {
                    const int s0 = (16 * kt + 4 * q + 4 * m) & 31;
                    bf[t][kt] = *(const f16x8*)(
                        stgw + (t * 16 + m) * 128 + (s0 << 2));
                }
            LDS_FENCE();   // reads ordered before next batch's slice writes
            cur = nxt;
        }
    }
}

extern "C" void kernel_launch(void* const* d_in, const int* in_sizes, int n_in,
                              void* d_out, int out_size, void* d_ws, size_t ws_size,
                              hipStream_t stream) {
    (void)n_in; (void)out_size;
    const float* P  = (const float*)d_in[0];
    const float* WI = (const float*)d_in[1];
    const float* NV = (const float*)d_in[2];
    const float* AL = (const float*)d_in[3];
    const float* BE = (const float*)d_in[4];
    const float* RR = (const float*)d_in[5];
    const float* W0 = (const float*)d_in[6];
    const float* W1 = (const float*)d_in[7];
    const float* W2 = (const float*)d_in[8];
    const float* W3 = (const float*)d_in[9];
    const float* W4 = (const float*)d_in[10];
    const float* W5 = (const float*)d_in[11];
    const float* W6 = (const float*)d_in[12];
    f16*   ws  = (f16*)d_ws;
    float* Out = (float*)d_out;

    const int Bn = in_sizes[0] / 3;     // 1,048,576
    const int grid = Bn / SPB;          // 512 blocks of 256 threads

    // ws_size fixed per session -> same path every call (graph-safe).
    if (ws_size >= WS_BYTES) {
        hipLaunchKernelGGL(pack_weights_kernel, dim3((WCHUNKS + 255) / 256),
                           dim3(256), 0, stream, W0, W1, W2, W3, W4, W5, W6, ws);
        hipLaunchKernelGGL((nrc_mlp_kernel<1>), dim3(grid), dim3(BLOCK), 0, stream,
                           P, WI, NV, AL, BE, RR, ws,
                           W0, W1, W2, W3, W4, W5, W6, Out);
    } else {
        hipLaunchKernelGGL((nrc_mlp_kernel<0>), dim3(grid), dim3(BLOCK), 0, stream,
                           P, WI, NV, AL, BE, RR, ws,
                           W0, W1, W2, W3, W4, W5, W6, Out);
    }
}

// Round 10
// 157.063 us; speedup vs baseline: 1.2361x; 1.0207x over previous
//
#include <hip/hip_runtime.h>

// NRC fused encode + 7-layer W=64 MLP. R23 = R22's stall surgery with the
// staging rotation REVERTED to the verified R21 layout.
//
// R22 post-mortem (correctness fail, absmax 0.39): rot=(2*lane)&31 made the
// read base slot s0=(16kt+4q+2m)&31 misaligned (s0 mod 4 = 2 for odd m), so
// the 16B ds_read_b128 wrapped past the &31 boundary and read 8 bytes of the
// NEXT sample's row. The 4-dword-aligned invariant of the slot rotation is
// load-width-mandatory. Conflicts it targeted = ~2.5% of runtime; accepted.
// R23 keeps R22's two untested changes:
//   1. kt-granularity weight double-buffer (wcur/wnxt prefetched one full
//      phase ahead -> ~120cy ds_read latency hidden; paid by W0->LDS
//      (48 units = 49152B) and W6->2 persistent reg frags).
//      LDS 81920B -> 2 blocks/CU = exactly 160KB.
//   2. Per-tile repack->MFMA interleave: for t {repack(t); 4 MFMAs kt0} --
//      MFMA pipe gets fresh work every ~70cy instead of per-layer drain.
// Structure (R21-verified): intra-wave software pipeline, BLOCK=256,
// launch_bounds(256,2) big-register regime, wave-private 8KB staging slice,
// encode slices of batch b+1 interleaved into batch b's layer phases,
// NO in-loop barriers. R21 baseline: 57.6us, zero spills.
//
// 16x16x32 f16 fragment maps (verified):
//   A[m=lane&15][k=(lane>>4)*8+j], B[k=(lane>>4)*8+j][n=lane&15],
//   D[row=(lane>>4)*4+r][col=lane&15]  (4 blocks mt: row=mt*16+q*4+r)
// Chaining: bf[kt]=concat(relu(pack(acc[2kt])), relu(pack(acc[2kt+1])));
// k-index mismatch absorbed by permuting W1..W5,W6 columns with
// tau(x)=32(x>>5)+16((x&7)>>2)+4((x>>3)&3)+(x&3) at pack time.
// Staging slice (per wave, 8KB): sample row n at +n*128, dword D at slot
// (D+4n)&31; write rot=(4*lane)&31, read s0=(16kt+4q+4m)&31  [R21-verified;
// slot groups stay 4-aligned -> b128 reads never wrap].

typedef _Float16 f16;
typedef f16 f16x2 __attribute__((ext_vector_type(2)));
typedef f16 f16x4 __attribute__((ext_vector_type(4)));
typedef f16 f16x8 __attribute__((ext_vector_type(8)));
typedef float f32x4 __attribute__((ext_vector_type(4)));

#define MFMA32(A, B, C) __builtin_amdgcn_mfma_f32_16x16x32_f16(A, B, C, 0, 0, 0)
#define LDS_FENCE() __asm__ volatile("" ::: "memory")

static constexpr int TILES  = 4;        // 16-sample tiles per batch
static constexpr int WAVES  = 4;
static constexpr int BLOCK  = WAVES * 64;    // 256
static constexpr int NB     = 8;        // batches per wave
static constexpr int SPB    = WAVES * NB * 64;   // 2048

static constexpr int    WUNITS   = 50;      // packed image: 48 hidden + 2 W6
static constexpr int    WCHUNKS  = WUNITS * 64;           // 3200 x 16B
static constexpr size_t WS_BYTES = (size_t)WCHUNKS * 16;  // 51200
static constexpr int    LDSUNITS = 48;      // W0..W5 in LDS
static constexpr int    LDSCHNK  = LDSUNITS * 64;         // 3072
static constexpr int    LDS_WEI  = LDSUNITS * 1024;       // 49152
static constexpr int    LDS_STG  = WAVES * 8192;          // 32768
static constexpr int    LDS_TOT  = LDS_WEI + LDS_STG;     // 81920 (2/CU=160KB)

__host__ __device__ __forceinline__ int tau(int x) {
    return (x & 32) + ((x & 7) >> 2) * 16 + ((x >> 3) & 3) * 4 + (x & 3);
}

__device__ __forceinline__ f16x2 pkh(float a, float b) {
    return __builtin_bit_cast(f16x2, __builtin_amdgcn_cvt_pkrtz(a, b));
}

__device__ __forceinline__ f16x4 cat22(f16x2 a, f16x2 b) {
    return __builtin_shufflevector(a, b, 0, 1, 2, 3);
}

__device__ __forceinline__ f16x8 cat44(f16x4 a, f16x4 b) {
    return __builtin_shufflevector(a, b, 0, 1, 2, 3, 4, 5, 6, 7);
}

__device__ __forceinline__ f16x4 pack4(f32x4 v) {
    return cat22(pkh(v[0], v[1]), pkh(v[2], v[3]));
}

// atan2(y,x) / (2*pi)
__device__ __forceinline__ float fast_atan2_rev(float y, float x) {
    const float ax = __builtin_fabsf(x), ay = __builtin_fabsf(y);
    const float mx = fmaxf(ax, ay), mn = fminf(ax, ay);
    const float a = mn * __builtin_amdgcn_rcpf(fmaxf(mx, 1e-30f));
    const float s = a * a;
    float r = a * (0.99997726f + s * (-0.33262347f + s * (0.19354346f +
              s * (-0.11643287f + s * (0.05265332f - s * 0.01172120f)))));
    if (ay > ax) r = 1.5707963268f - r;
    if (x < 0.0f) r = 3.1415926536f - r;
    r = (y < 0.0f) ? -r : r;
    return r * 0.15915494309189535f;
}

// acos(x), |err| <= 6.8e-5 rad
__device__ __forceinline__ float fast_acos(float x) {
    const float ax = __builtin_fabsf(x);
    const float t = __builtin_amdgcn_sqrtf(1.0f - ax);
    const float p = t * (1.5707288f + ax * (-0.2121144f +
                    ax * (0.0742610f - ax * 0.0187293f)));
    return (x < 0.0f) ? (3.1415926536f - p) : p;
}

// one-blob: out[i]=exp(-8(x-c_i)^2) via exp ladder (2 transcendentals)
__device__ __forceinline__ void blob4(float x, float* out) {
    const float dx = x - 0.125f;
    const float E0 = __expf(-8.0f * dx * dx);
    const float R  = __expf(4.0f * dx);
    const float t1 = R * 0.60653066f;
    const float t2 = R * 0.22313016f;
    const float t3 = R * 0.082084999f;
    out[0] = E0;
    out[1] = E0 * t1;
    out[2] = out[1] * t2;
    out[3] = out[2] * t3;
}

// compute packed-weight chunk c (= unit*64 + lane2) from the f32 weights
__device__ __forceinline__ f16x8 make_wchunk(
    int c, const float* __restrict__ W0, const float* __restrict__ W1,
    const float* __restrict__ W2, const float* __restrict__ W3,
    const float* __restrict__ W4, const float* __restrict__ W5,
    const float* __restrict__ W6)
{
    const int lane2 = c & 63;
    const int unit  = c >> 6;
    const int q = lane2 >> 4, m = lane2 & 15;
    f16x8 v;
    if (unit < 48) {
        const int l = unit >> 3, kt = (unit & 7) >> 2, mt = unit & 3;
        const float* Ws[6] = {W0, W1, W2, W3, W4, W5};
        const float* __restrict__ Wl = Ws[l];
#pragma unroll
        for (int j = 0; j < 8; ++j) {
            const int x = kt * 32 + q * 8 + j;
            const int src = (l == 0) ? x : tau(x);
            v[j] = (f16)Wl[(mt * 16 + m) * 64 + src];
        }
    } else {
        const int kt = unit - 48;
#pragma unroll
        for (int j = 0; j < 8; ++j) {
            const int src = tau(kt * 32 + q * 8 + j);
            v[j] = (m < 3) ? (f16)W6[m * 64 + src] : (f16)0.0f;
        }
    }
    return v;
}

__global__ __launch_bounds__(256, 1) void pack_weights_kernel(
    const float* __restrict__ W0, const float* __restrict__ W1,
    const float* __restrict__ W2, const float* __restrict__ W3,
    const float* __restrict__ W4, const float* __restrict__ W5,
    const float* __restrict__ W6, f16* __restrict__ ws)
{
    const int c = (int)blockIdx.x * 256 + threadIdx.x;
    if (c >= WCHUNKS) return;
    *(f16x8*)(ws + (size_t)c * 8) = make_wchunk(c, W0, W1, W2, W3, W4, W5, W6);
}

// async global->LDS DMA, 16B per lane (wave-uniform LDS base + lane*16).
__device__ __forceinline__ void async_ld16(const void* g, void* l) {
    __builtin_amdgcn_global_load_lds(
        (const __attribute__((address_space(1))) void*)g,
        (__attribute__((address_space(3))) void*)l,
        16, 0, 0);
}

struct EncIn {
    float pv[3], wv[3], nv[3], av[3], bv[3], rv;
};

__device__ __forceinline__ EncIn load_inputs(
    const float* __restrict__ P,  const float* __restrict__ WI,
    const float* __restrict__ NV, const float* __restrict__ AL,
    const float* __restrict__ BE, const float* __restrict__ RR, int s)
{
    EncIn e;
#pragma unroll
    for (int d = 0; d < 3; ++d) {
        e.pv[d] = P [s * 3 + d];
        e.wv[d] = WI[s * 3 + d];
        e.nv[d] = NV[s * 3 + d];
        e.av[d] = AL[s * 3 + d];
        e.bv[d] = BE[s * 3 + d];
    }
    e.rv = RR[s];
    return e;
}

// one encode slice (k = 0..5), writes its features to the wave-private slice.
// k is a compile-time constant at every call site (unrolled layer loop).
__device__ __forceinline__ void enc_slice(
    int k, const EncIn& e, unsigned char* myrow, int rot, float* abn)
{
    auto put = [&](int D, f16x2 a, f16x2 b) {
        *(f16x4*)(myrow + (((D + rot) & 31) << 2)) = cat22(a, b);
    };
    if (k <= 2) {
        const int d = k;   // freq embed dim d
        float sA[6], cA[6];
        const float fr = __builtin_amdgcn_fractf(e.pv[d] * 0.5f);
        sA[0] = __builtin_amdgcn_sinf(fr);
        cA[0] = __builtin_amdgcn_cosf(fr);
#pragma unroll
        for (int kk = 1; kk < 6; ++kk) {
            const float s2 = sA[kk-1] * sA[kk-1];
            const float sc = sA[kk-1] * cA[kk-1];
            cA[kk] = fmaf(-2.0f, s2, 1.0f);
            sA[kk] = sc + sc;
        }
        put(6*d + 0, pkh(sA[0], sA[1]), pkh(sA[2], sA[3]));
        put(6*d + 2, pkh(sA[4], sA[5]), pkh(cA[0], cA[1]));
        put(6*d + 4, pkh(cA[2], cA[3]), pkh(cA[4], cA[5]));
    } else if (k <= 4) {
        const int which = k - 3;   // 0: wi, 1: n
        const float dx = which ? e.nv[0] : e.wv[0];
        const float dy = which ? e.nv[1] : e.wv[1];
        const float dz = which ? e.nv[2] : e.wv[2];
        const int D0 = 18 + which * 4;
        const float nr = __builtin_amdgcn_sqrtf(dx*dx + dy*dy + dz*dz) + 1e-8f;
        const float u  = fast_atan2_rev(dy, dx) + 0.5f;
        float zc = dz * __builtin_amdgcn_rcpf(nr);
        zc = fminf(fmaxf(zc, -1.0f + 1e-6f), 1.0f - 1e-6f);
        const float vv = fast_acos(zc) * 0.3183098861837907f;
        float ob[8];
        blob4(u,  &ob[0]);
        blob4(vv, &ob[4]);
        put(D0,     pkh(ob[0], ob[1]), pkh(ob[2], ob[3]));
        put(D0 + 2, pkh(ob[4], ob[5]), pkh(ob[6], ob[7]));
    } else {
        float ob[4];
        blob4(1.0f - __expf(-e.rv), ob);
        put(26, pkh(ob[0], ob[1]), pkh(ob[2], ob[3]));
        put(28, pkh(e.av[0], e.av[1]), pkh(e.av[2], e.bv[0]));
        put(30, pkh(e.bv[1], e.bv[2]), pkh(1.0f, 1.0f));
        abn[0] = e.av[0] + e.bv[0];
        abn[1] = e.av[1] + e.bv[1];
        abn[2] = e.av[2] + e.bv[2];
    }
}

template<int PACKED>
__global__ __launch_bounds__(BLOCK, 2) void nrc_mlp_kernel(
    const float* __restrict__ P,  const float* __restrict__ WI,
    const float* __restrict__ NV, const float* __restrict__ AL,
    const float* __restrict__ BE, const float* __restrict__ RR,
    const f16*   __restrict__ ws,
    const float* __restrict__ W0, const float* __restrict__ W1,
    const float* __restrict__ W2, const float* __restrict__ W3,
    const float* __restrict__ W4, const float* __restrict__ W5,
    const float* __restrict__ W6, float* __restrict__ Out)
{
    // [0,49152): W0..W5 frag image (packed unit u at u*1024 + lane*16).
    // [49152,81920): 4 wave-private 8KB slices (64 rows x 128B, rotated).
    __shared__ __attribute__((aligned(16))) unsigned char smem[LDS_TOT];

    const int tid  = threadIdx.x;
    const int lane = tid & 63;
    const int w    = tid >> 6;
    const int q    = lane >> 4;
    const int m    = lane & 15;
    const int wave_base = (int)blockIdx.x * SPB + w * (NB * 64);

    unsigned char* const stgw  = smem + LDS_WEI + w * 8192;
    unsigned char* const myrow = stgw + lane * 128;
    const int rot = (4 * lane) & 31;            // R21-verified (4-aligned)
    unsigned char* const wbl   = smem + lane * 16;

    // ---- weight image W0..W5 -> LDS (async DMA / VALU fallback) ----
    if (PACKED) {
#pragma unroll
        for (int i = 0; i < LDSCHNK / BLOCK; ++i) {
            const int c = i * BLOCK + tid;
            async_ld16(ws + (size_t)c * 8, smem + c * 16);
        }
    } else {
#pragma unroll
        for (int i = 0; i < LDSCHNK / BLOCK; ++i) {
            const int c = i * BLOCK + tid;
            *(f16x8*)(smem + c * 16) =
                make_wchunk(c, W0, W1, W2, W3, W4, W5, W6);
        }
    }

    // ---- W6: 2 persistent register fragments (packed units 48,49) ----
    f16x8 w6a, w6b;
    if (PACKED) {
        w6a = *(const f16x8*)(ws + (size_t)(3072 + lane) * 8);
        w6b = *(const f16x8*)(ws + (size_t)(3136 + lane) * 8);
    } else {
        w6a = make_wchunk(3072 + lane, W0, W1, W2, W3, W4, W5, W6);
        w6b = make_wchunk(3136 + lane, W0, W1, W2, W3, W4, W5, W6);
    }

    // ---- prologue: encode batch 0 into the wave-private slice ----
    float ab_cur[3], abn[3];
    {
        EncIn e0 = load_inputs(P, WI, NV, AL, BE, RR, wave_base + lane);
#pragma unroll
        for (int k = 0; k < 6; ++k)
            enc_slice(k, e0, myrow, rot, abn);
        ab_cur[0] = abn[0]; ab_cur[1] = abn[1]; ab_cur[2] = abn[2];
    }

    __syncthreads();   // weight image complete (the ONLY barrier)

    const f16x4 zero4 = {(f16)0.0f, (f16)0.0f, (f16)0.0f, (f16)0.0f};
    const f32x4 ZF = {0.0f, 0.0f, 0.0f, 0.0f};

    // ---- preload layer 0's weight phases (double buffer) ----
    f16x8 wcur[4], wnxt[4];
#pragma unroll
    for (int mt = 0; mt < 4; ++mt)
        wcur[mt] = *(const f16x8*)(wbl + mt * 1024);
#pragma unroll
    for (int mt = 0; mt < 4; ++mt)
        wnxt[mt] = *(const f16x8*)(wbl + (4 + mt) * 1024);

    // ---- read batch 0's B fragments ----
    f16x8 bf[TILES][2];
    LDS_FENCE();
#pragma unroll
    for (int t = 0; t < TILES; ++t)
#pragma unroll
        for (int kt = 0; kt < 2; ++kt) {
            const int s0 = (16 * kt + 4 * q + 4 * m) & 31;   // 4-aligned
            bf[t][kt] = *(const f16x8*)(stgw + (t * 16 + m) * 128 + (s0 << 2));
        }
    LDS_FENCE();

    EncIn cur = load_inputs(P, WI, NV, AL, BE, RR, wave_base + 64 + lane);
    EncIn nxt = cur;

    // ---- batch loop: layers(b) interleaved with encode slices(b+1) ----
#pragma unroll 1
    for (int b = 0; b < NB; ++b) {
        const bool hn = (b + 1 < NB);
        if (b + 2 < NB)
            nxt = load_inputs(P, WI, NV, AL, BE, RR,
                              wave_base + (b + 2) * 64 + lane);

        f32x4 acc[TILES][4];
#pragma unroll
        for (int layer = 0; layer < 6; ++layer) {
            __builtin_amdgcn_s_setprio(1);
            // per-tile: repack(prev layer) then kt0 MFMAs -- MFMA pipe gets
            // 4 fresh independent MFMAs every ~70cy of repack VALU.
#pragma unroll
            for (int t = 0; t < TILES; ++t) {
                if (layer > 0) {
                    f16x4 pk[4];
#pragma unroll
                    for (int mt = 0; mt < 4; ++mt)
                        pk[mt] = __builtin_elementwise_max(pack4(acc[t][mt]), zero4);
                    bf[t][0] = cat44(pk[0], pk[1]);   // tau absorbed next layer
                    bf[t][1] = cat44(pk[2], pk[3]);
                }
#pragma unroll
                for (int mt = 0; mt < 4; ++mt)
                    acc[t][mt] = MFMA32(wcur[mt], bf[t][0], ZF);
            }
            __builtin_amdgcn_s_setprio(0);
            // prefetch kt0 of next layer (wraps to layer 0 for next batch)
            {
                const int nl = (layer + 1) % 6;
#pragma unroll
                for (int mt = 0; mt < 4; ++mt)
                    wcur[mt] = *(const f16x8*)(wbl + (nl * 8 + mt) * 1024);
            }
            // encode slice of batch b+1 in the kt0-MFMA shadow (VALU pipe)
            if (hn) enc_slice(layer, cur, myrow, rot, abn);
            __builtin_amdgcn_s_setprio(1);
#pragma unroll
            for (int t = 0; t < TILES; ++t)
#pragma unroll
                for (int mt = 0; mt < 4; ++mt)
                    acc[t][mt] = MFMA32(wnxt[mt], bf[t][1], acc[t][mt]);
            __builtin_amdgcn_s_setprio(0);
            // prefetch kt1 of next layer
            {
                const int nl = (layer + 1) % 6;
#pragma unroll
                for (int mt = 0; mt < 4; ++mt)
                    wnxt[mt] = *(const f16x8*)(wbl + (nl * 8 + 4 + mt) * 1024);
            }
        }

        // ---- epilogue: repack layer5, W6 (register frags) + scale + store --
        {
#pragma unroll
            for (int t = 0; t < TILES; ++t) {
                f16x4 pk[4];
#pragma unroll
                for (int mt = 0; mt < 4; ++mt)
                    pk[mt] = __builtin_elementwise_max(pack4(acc[t][mt]), zero4);
                bf[t][0] = cat44(pk[0], pk[1]);
                bf[t][1] = cat44(pk[2], pk[3]);
            }
            const int rbase = wave_base + b * 64;
            f32x4 oz[TILES];
#pragma unroll
            for (int t = 0; t < TILES; ++t) oz[t] = MFMA32(w6a, bf[t][0], ZF);
#pragma unroll
            for (int t = 0; t < TILES; ++t) oz[t] = MFMA32(w6b, bf[t][1], oz[t]);
#pragma unroll
            for (int t = 0; t < TILES; ++t) {
                // ab of sample t*16+m lives in lane t*16+m's registers
                const float s0 = __shfl(ab_cur[0], t * 16 + m);
                const float s1 = __shfl(ab_cur[1], t * 16 + m);
                const float s2 = __shfl(ab_cur[2], t * 16 + m);
                if (lane < 16) {   // q==0: D rows 0..2 = out channels, col m
                    const int s = rbase + t * 16 + m;
                    float* o = Out + s * 3;
                    o[0] = oz[t][0] * s0;
                    o[1] = oz[t][1] * s1;
                    o[2] = oz[t][2] * s2;
                }
            }
        }

        // ---- batch switch: pull in batch b+1 (written during the layers) ----
        if (hn) {
            ab_cur[0] = abn[0]; ab_cur[1] = abn[1]; ab_cur[2] = abn[2];
            LDS_FENCE();   // slice writes ordered before reads (same wave)
#pragma unroll
            for (int t = 0; t < TILES; ++t)
#pragma unroll
                for (int kt = 0; kt < 2; ++kt) {
                    const int s0 = (16 * kt + 4 * q + 4 * m) & 31;   // 4-aligned
                    bf[t][kt] = *(const f16x8*)(
                        stgw + (t * 16 + m) * 128 + (s0 << 2));
                }
            LDS_FENCE();   // reads ordered before next batch's slice writes
            cur = nxt;
        }
    }
}

extern "C" void kernel_launch(void* const* d_in, const int* in_sizes, int n_in,
                              void* d_out, int out_size, void* d_ws, size_t ws_size,
                              hipStream_t stream) {
    (void)n_in; (void)out_size;
    const float* P  = (const float*)d_in[0];
    const float* WI = (const float*)d_in[1];
    const float* NV = (const float*)d_in[2];
    const float* AL = (const float*)d_in[3];
    const float* BE = (const float*)d_in[4];
    const float* RR = (const float*)d_in[5];
    const float* W0 = (const float*)d_in[6];
    const float* W1 = (const float*)d_in[7];
    const float* W2 = (const float*)d_in[8];
    const float* W3 = (const float*)d_in[9];
    const float* W4 = (const float*)d_in[10];
    const float* W5 = (const float*)d_in[11];
    const float* W6 = (const float*)d_in[12];
    f16*   ws  = (f16*)d_ws;
    float* Out = (float*)d_out;

    const int Bn = in_sizes[0] / 3;     // 1,048,576
    const int grid = Bn / SPB;          // 512 blocks of 256 threads

    // ws_size fixed per session -> same path every call (graph-safe).
    if (ws_size >= WS_BYTES) {
        hipLaunchKernelGGL(pack_weights_kernel, dim3((WCHUNKS + 255) / 256),
                           dim3(256), 0, stream, W0, W1, W2, W3, W4, W5, W6, ws);
        hipLaunchKernelGGL((nrc_mlp_kernel<1>), dim3(grid), dim3(BLOCK), 0, stream,
                           P, WI, NV, AL, BE, RR, ws,
                           W0, W1, W2, W3, W4, W5, W6, Out);
    } else {
        hipLaunchKernelGGL((nrc_mlp_kernel<0>), dim3(grid), dim3(BLOCK), 0, stream,
                           P, WI, NV, AL, BE, RR, ws,
                           W0, W1, W2, W3, W4, W5, W6, Out);
    }
}